// Round 13
// baseline (899.418 us; speedup 1.0000x reference)
//
#include <hip/hip_runtime.h>
#include <math.h>

#define DEPTH 4
#define DMODEL 512
#define DH 64
#define MF 256
#define FFD 2048
#define SEQN 4096
#define NROWS 8192

typedef __bf16 bf16_t;
typedef bf16_t bf16x8 __attribute__((ext_vector_type(8)));
typedef bf16_t bf16x4 __attribute__((ext_vector_type(4)));
typedef bf16_t bf16x2 __attribute__((ext_vector_type(2)));
typedef float f32x4v __attribute__((ext_vector_type(4)));

static constexpr float DN = 0.35355339059327373f;   // 64^-0.25
static constexpr float RATIO = 0.0625f;             // 256^-0.5
static constexpr float EPSK = 1e-4f;

__device__ __forceinline__ float gelu_exact(float x) {
    return 0.5f * x * (1.0f + erff(x * 0.70710678118654752f));
}

#define AS1(p) ((const __attribute__((address_space(1))) void*)(p))
#define AS3(p) ((__attribute__((address_space(3))) void*)(p))

template <int N> __device__ __forceinline__ void wait_vmcnt() {
    if constexpr (N == 0) asm volatile("s_waitcnt vmcnt(0)" ::: "memory");
    else if constexpr (N == 1) asm volatile("s_waitcnt vmcnt(1)" ::: "memory");
    else if constexpr (N == 2) asm volatile("s_waitcnt vmcnt(2)" ::: "memory");
    else if constexpr (N == 3) asm volatile("s_waitcnt vmcnt(3)" ::: "memory");
    else if constexpr (N == 4) asm volatile("s_waitcnt vmcnt(4)" ::: "memory");
    else if constexpr (N == 5) asm volatile("s_waitcnt vmcnt(5)" ::: "memory");
    else if constexpr (N == 6) asm volatile("s_waitcnt vmcnt(6)" ::: "memory");
    else if constexpr (N == 8) asm volatile("s_waitcnt vmcnt(8)" ::: "memory");
    else asm volatile("s_waitcnt vmcnt(12)" ::: "memory");
}

// ---------------- LayerNorm -> bf16 (no residual) ----------------
__global__ __launch_bounds__(256) void ln_kernel(const float* __restrict__ h,
                                                 const float* __restrict__ g,
                                                 const float* __restrict__ b,
                                                 bf16_t* __restrict__ y) {
    int row = blockIdx.x, tid = threadIdx.x;
    const float* hr = h + (size_t)row * DMODEL;
    float v0 = hr[tid], v1 = hr[tid + 256];
    __shared__ float s_sum[256], s_sq[256];
    s_sum[tid] = v0 + v1;
    s_sq[tid] = v0 * v0 + v1 * v1;
    __syncthreads();
    for (int off = 128; off > 0; off >>= 1) {
        if (tid < off) { s_sum[tid] += s_sum[tid + off]; s_sq[tid] += s_sq[tid + off]; }
        __syncthreads();
    }
    float mu = s_sum[0] * (1.0f / DMODEL);
    float var = s_sq[0] * (1.0f / DMODEL) - mu * mu;
    float rstd = rsqrtf(var + 1e-5f);
    bf16_t* yr = y + (size_t)row * DMODEL;
    yr[tid]       = (bf16_t)((v0 - mu) * rstd * g[tid] + b[tid]);
    yr[tid + 256] = (bf16_t)((v1 - mu) * rstd * g[tid + 256] + b[tid + 256]);
}

// ---------------- fused: h += P (bf16); LayerNorm(h) -> bf16; h written back ----------------
__global__ __launch_bounds__(256) void ln_add_kernel(float* __restrict__ h,
                                                     const bf16_t* __restrict__ p,
                                                     const float* __restrict__ g,
                                                     const float* __restrict__ b,
                                                     bf16_t* __restrict__ y) {
    int row = blockIdx.x, tid = threadIdx.x;
    float* hr = h + (size_t)row * DMODEL;
    const bf16_t* pr = p + (size_t)row * DMODEL;
    float2 hv = *(const float2*)(hr + 2 * tid);
    bf16x2 pv = *(const bf16x2*)(pr + 2 * tid);
    float v0 = hv.x + (float)pv[0];
    float v1 = hv.y + (float)pv[1];
    float2 outv; outv.x = v0; outv.y = v1;
    *(float2*)(hr + 2 * tid) = outv;
    __shared__ float s_sum[256], s_sq[256];
    s_sum[tid] = v0 + v1;
    s_sq[tid] = v0 * v0 + v1 * v1;
    __syncthreads();
    for (int off = 128; off > 0; off >>= 1) {
        if (tid < off) { s_sum[tid] += s_sum[tid + off]; s_sq[tid] += s_sq[tid + off]; }
        __syncthreads();
    }
    float mu = s_sum[0] * (1.0f / DMODEL);
    float var = s_sq[0] * (1.0f / DMODEL) - mu * mu;
    float rstd = rsqrtf(var + 1e-5f);
    bf16x2 ov;
    ov[0] = (bf16_t)((v0 - mu) * rstd * g[2 * tid] + b[2 * tid]);
    ov[1] = (bf16_t)((v1 - mu) * rstd * g[2 * tid + 1] + b[2 * tid + 1]);
    *(bf16x2*)(y + (size_t)row * DMODEL + 2 * tid) = ov;
}

// ---------------- tail: h += P (bf16) ----------------
__global__ __launch_bounds__(256) void add_kernel(float* __restrict__ h,
                                                  const bf16_t* __restrict__ p) {
    size_t i = ((size_t)blockIdx.x * 256 + threadIdx.x) * 4;
    float4 hv = *(const float4*)(h + i);
    bf16x4 pv = *(const bf16x4*)(p + i);
    hv.x += (float)pv[0]; hv.y += (float)pv[1];
    hv.z += (float)pv[2]; hv.w += (float)pv[3];
    *(float4*)(h + i) = hv;
}

// ---------------- weight transpose+convert; blockIdx.y = layer offset ----------------
__global__ __launch_bounds__(256) void wconv_all(const float* __restrict__ Wqkv,
                                                 const float* __restrict__ Wo,
                                                 const float* __restrict__ Wff1,
                                                 const float* __restrict__ Wff2,
                                                 bf16_t* __restrict__ wslot) {
    __shared__ float t[32][33];
    int layer = blockIdx.y;
    int bid = blockIdx.x;
    const float* W; bf16_t* Wt; int K, N, nx, lb;
    bf16_t* slot = wslot + (size_t)layer * 3407872;
    if (bid < 768)       { W = Wqkv + (size_t)layer * 786432;  Wt = slot;           K = 512;  N = 1536; nx = 48; lb = bid; }
    else if (bid < 1024) { W = Wo   + (size_t)layer * 262144;  Wt = slot + 786432;  K = 512;  N = 512;  nx = 16; lb = bid - 768; }
    else if (bid < 2048) { W = Wff1 + (size_t)layer * 1048576; Wt = slot + 1048576; K = 512;  N = 2048; nx = 64; lb = bid - 1024; }
    else                 { W = Wff2 + (size_t)layer * 1048576; Wt = slot + 2097152; K = 2048; N = 512;  nx = 16; lb = bid - 2048; }
    int n0 = (lb % nx) * 32, k0 = (lb / nx) * 32;
    int tx = threadIdx.x & 31, ty = threadIdx.x >> 5;
#pragma unroll
    for (int i = 0; i < 32; i += 8)
        t[ty + i][tx] = W[(size_t)(k0 + ty + i) * N + n0 + tx];
    __syncthreads();
#pragma unroll
    for (int i = 0; i < 32; i += 8)
        Wt[(size_t)(n0 + ty + i) * K + k0 + tx] = (bf16_t)t[tx][ty + i];
}

// ---------------- proj -> bf16 ----------------
__global__ __launch_bounds__(256) void pconv_kernel(const float* __restrict__ proj,
                                                    bf16_t* __restrict__ projb) {
    int i = (blockIdx.x * 256 + threadIdx.x) * 4;
    float4 v = *(const float4*)(proj + i);
    bf16x4 o;
    o[0] = (bf16_t)v.x; o[1] = (bf16_t)v.y; o[2] = (bf16_t)v.z; o[3] = (bf16_t)v.w;
    *(bf16x4*)(projb + i) = o;
}

// ---------------- 128x64 BK=32 P=4 pipelined MFMA GEMM, hoisted addressing ----------------
template <int BM, int BN, int BK, int P, int ACT, int RES, int WF, int WB, int QKVE>
__global__ __launch_bounds__(256) void gemm_pipe(const bf16_t* __restrict__ A,
                                                 const bf16_t* __restrict__ Bt,
                                                 const float* __restrict__ bias,
                                                 float* __restrict__ Cf,
                                                 bf16_t* __restrict__ Cb,
                                                 bf16_t* __restrict__ Vt,
                                                 int N, int K) {
    static_assert(BK == 32, "BK fixed at 32 (KS==1)");
    constexpr int MR = BM / 2 / 16;
    constexpr int NR = BN / 2 / 16;
    constexpr int CH = BK / 8;
    constexpr int SWZ = CH - 1;
    constexpr int TILE = (BM + BN) * BK;
    constexpr int L = TILE / 8 / 256;
    __shared__ __attribute__((aligned(16))) bf16_t smem[P * TILE];
    int tid = threadIdx.x;
    int wv = tid >> 6, ln = tid & 63;
    int gx = gridDim.x;
    int lin = blockIdx.y * gx + blockIdx.x;
    int per = (gx * gridDim.y) >> 3;
    int orig = (lin & 7) * per + (lin >> 3);
    int m0 = (orig / gx) * BM, n0 = (orig % gx) * BN;
    int wr = (wv >> 1) * (MR * 16), wc = (wv & 1) * (NR * 16);
    int lr = ln & 15, kq8 = ln >> 4;
    int nsteps = K / BK;

    // hoisted staging addresses (K-invariant)
    const bf16_t* gsrc[L];
    int ldst[L];
#pragma unroll
    for (int i = 0; i < L; i++) {
        int c = i * 256 + tid;
        int cb = i * 256 + (tid & ~63);
        bool inA = (c < BM * CH);
        int cc = inA ? c : c - BM * CH;
        int row = cc / CH, ch = cc % CH;
        const bf16_t* mat = inA ? A : Bt;
        int r0 = inA ? m0 : n0;
        int chs = ch ^ ((row ^ (row >> 2)) & SWZ);
        gsrc[i] = mat + (size_t)(r0 + row) * K + chs * 8;
        ldst[i] = cb * 8;
    }
    auto stage = [&](int tile, int sb) {
        int k0 = tile * BK;
        bf16_t* dst = smem + sb * TILE;
#pragma unroll
        for (int i = 0; i < L; i++)
            __builtin_amdgcn_global_load_lds(AS1(gsrc[i] + k0), AS3(dst + ldst[i]), 16, 0, 0);
    };

    // hoisted fragment-read offsets (K-invariant, KS==1)
    int aoff[MR], boff[NR];
#pragma unroll
    for (int m = 0; m < MR; m++) {
        int row = wr + m * 16 + lr;
        aoff[m] = (row * CH + (kq8 ^ ((row ^ (row >> 2)) & SWZ))) * 8;
    }
#pragma unroll
    for (int n = 0; n < NR; n++) {
        int row = wc + n * 16 + lr;
        boff[n] = BM * BK + (row * CH + (kq8 ^ ((row ^ (row >> 2)) & SWZ))) * 8;
    }

    f32x4v acc[MR][NR] = {};
#pragma unroll
    for (int p = 0; p < P - 1; ++p) stage(p, p);

    int cur = 0;
    for (int t = 0; t < nsteps; ++t) {
        int rem = nsteps - 1 - t;
        if (rem >= P - 2) wait_vmcnt<(P - 2) * L>();
        else if (rem == 1) wait_vmcnt<L>();
        else wait_vmcnt<0>();
        __builtin_amdgcn_s_barrier();
        asm volatile("" ::: "memory");
        if (t + P - 1 < nsteps) {
            int sb = cur - 1; if (sb < 0) sb = P - 1;
            stage(t + P - 1, sb);
        }
        const bf16_t* base = smem + cur * TILE;
        bf16x8 af[MR], bfr[NR];
#pragma unroll
        for (int m = 0; m < MR; m++) af[m] = *(const bf16x8*)&base[aoff[m]];
#pragma unroll
        for (int n = 0; n < NR; n++) bfr[n] = *(const bf16x8*)&base[boff[n]];
        __builtin_amdgcn_s_setprio(1);
#pragma unroll
        for (int m = 0; m < MR; m++)
#pragma unroll
            for (int n = 0; n < NR; n++)
                acc[m][n] = __builtin_amdgcn_mfma_f32_16x16x32_bf16(af[m], bfr[n], acc[m][n], 0, 0, 0);
        __builtin_amdgcn_s_setprio(0);
        cur = (cur + 1 == P) ? 0 : cur + 1;
    }
    int rq = (ln >> 4) * 4;
    if (WB || QKVE) {
        // ---- coalesced bf16 epilogue through LDS (tile BM x BN) ----
        __syncthreads();
        bf16_t* T = smem;
        constexpr int S = BN + 8;
#pragma unroll
        for (int n = 0; n < NR; n++) {
            int col = wc + n * 16 + lr;
            float bcol = bias[n0 + col];
#pragma unroll
            for (int m = 0; m < MR; m++) {
#pragma unroll
                for (int r = 0; r < 4; r++) {
                    int row = wr + m * 16 + rq + r;
                    float v = acc[m][n][r] + bcol;
                    if (ACT == 1) v = gelu_exact(v);
                    int cs = (col & 7) | ((((col >> 3) ^ (row >> 3)) & (BN / 8 - 1)) << 3);
                    T[row * S + cs] = (bf16_t)v;
                }
            }
        }
        __syncthreads();
        if (!QKVE || n0 < 1024) {
            int ldc = QKVE ? 1024 : N;
#pragma unroll
            for (int i = 0; i < BM * BN / 8 / 256; i++) {
                int e = i * 2048 + tid * 8;
                int row = e / BN, c0 = e % BN;
                int ch = ((c0 >> 3) ^ (row >> 3)) & (BN / 8 - 1);
                bf16x8 v = *(const bf16x8*)&T[row * S + ch * 8];
                *(bf16x8*)&Cb[(size_t)(m0 + row) * ldc + n0 + c0] = v;
            }
        } else {
#pragma unroll
            for (int i = 0; i < BM * BN / 8 / 256; i++) {
                int u = i * 256 + tid;
                int d = u & (BN - 1), nb8 = (u / BN) * 8;
                bf16x8 v;
#pragma unroll
                for (int j = 0; j < 8; j++) {
                    int row = nb8 + j;
                    int cs = (d & 7) | ((((d >> 3) ^ (row >> 3)) & (BN / 8 - 1)) << 3);
                    v[j] = T[row * S + cs];
                }
                int gcol = n0 + d;
                int hh2 = (gcol >> 6) & 7, dd2 = gcol & 63;
                int grow = m0 + nb8;
                int bb = grow >> 12, nn = grow & 4095;
                *(bf16x8*)&Vt[(((size_t)bb * 8 + hh2) * 64 + dd2) * 4096 + nn] = v;
            }
        }
    } else {
#pragma unroll
        for (int n = 0; n < NR; n++) {
            int col = n0 + wc + n * 16 + lr;
            float bcol = bias[col];
#pragma unroll
            for (int m = 0; m < MR; m++) {
#pragma unroll
                for (int r = 0; r < 4; r++) {
                    int row = m0 + wr + m * 16 + rq + r;
                    float v = acc[m][n][r] + bcol;
                    if (ACT == 1) v = gelu_exact(v);
                    size_t idx = (size_t)row * N + col;
                    if (RES) Cf[idx] += v;
                    else Cf[idx] = v;
                }
            }
        }
    }
}

// ---------------- K-feature GEMM: dd[128n x 256m] per block, K=64 ----------------
template <int MODE>
__global__ __launch_bounds__(256) void feat_kernel(const bf16_t* __restrict__ qkvb,
                                                   const bf16_t* __restrict__ projb,
                                                   const float* __restrict__ kmaxb,
                                                   bf16_t* __restrict__ outp,
                                                   float* __restrict__ kpart,
                                                   float* __restrict__ ksum_part) {
    int bid = blockIdx.x;
    int bh = bid >> 5, tile = bid & 31;
    int b = bh >> 3, hh = bh & 7;
    int tid = threadIdx.x, wv = tid >> 6, ln = tid & 63;
    __shared__ __attribute__((aligned(16))) bf16_t As[128 * 64];
    __shared__ __attribute__((aligned(16))) bf16_t Bs[256 * 64];
    __shared__ float diag_s[128];
    __shared__ float red_s[256];
    __shared__ float ksp_s[256];
    int n0 = tile * 128;
    int qoff = 512 + hh * 64;
    int lrow8 = ln >> 3;
    int lchunk = ((ln & 7) ^ (lrow8 & 7)) * 8;
#pragma unroll
    for (int i = 0; i < 4; i++) {
        int e = wv * 4 + i;
        size_t src = (size_t)(b * SEQN + n0 + e * 8 + lrow8) * 1024 + qoff + lchunk;
        __builtin_amdgcn_global_load_lds(AS1(qkvb + src), AS3(&As[e * 512]), 16, 0, 0);
    }
#pragma unroll
    for (int i = 0; i < 8; i++) {
        int e = wv * 8 + i;
        size_t src = (size_t)(e * 8 + lrow8) * 64 + lchunk;
        __builtin_amdgcn_global_load_lds(AS1(projb + src), AS3(&Bs[e * 512]), 16, 0, 0);
    }
    __syncthreads();
    if (MODE == 2 && tid < 128) {
        float s = 0.f;
#pragma unroll
        for (int c = 0; c < 8; c++) {
            bf16x8 v = *(const bf16x8*)&As[tid * 64 + ((c ^ (tid & 7)) * 8)];
#pragma unroll
            for (int j = 0; j < 8; j++) { float f = (float)v[j]; s += f * f; }
        }
        diag_s[tid] = s * (0.5f * DN * DN);
    }
    int wr = (wv >> 1) * 64, wc = (wv & 1) * 128;
    int lr = ln & 15, kg = ln >> 4, rq = kg * 4;
    f32x4v acc[4][8] = {};
#pragma unroll
    for (int ks = 0; ks < 2; ks++) {
        int g = ks * 4 + kg;
        bf16x8 af[4], bfv[8];
#pragma unroll
        for (int m = 0; m < 4; m++) {
            int row = wr + m * 16 + lr;
            af[m] = *(const bf16x8*)&As[row * 64 + ((g ^ (row & 7)) * 8)];
        }
#pragma unroll
        for (int n = 0; n < 8; n++) {
            int row = wc + n * 16 + lr;
            bfv[n] = *(const bf16x8*)&Bs[row * 64 + ((g ^ (row & 7)) * 8)];
        }
#pragma unroll
        for (int m = 0; m < 4; m++)
#pragma unroll
            for (int n = 0; n < 8; n++)
                acc[m][n] = __builtin_amdgcn_mfma_f32_16x16x32_bf16(af[m], bfv[n], acc[m][n], 0, 0, 0);
    }
    if (MODE == 1) {
        float mx = -1e30f;
#pragma unroll
        for (int m = 0; m < 4; m++)
#pragma unroll
            for (int n = 0; n < 8; n++)
#pragma unroll
                for (int r = 0; r < 4; r++) mx = fmaxf(mx, acc[m][n][r]);
        red_s[tid] = mx * DN;
        __syncthreads();
        for (int off = 128; off > 0; off >>= 1) {
            if (tid < off) red_s[tid] = fmaxf(red_s[tid], red_s[tid + off]);
            __syncthreads();
        }
        if (tid == 0) kpart[bid] = red_s[0];
    } else {
        float kmx = kmaxb[bh];
        __syncthreads();
        float sj[8] = {};
#pragma unroll
        for (int m = 0; m < 4; m++) {
#pragma unroll
            for (int n = 0; n < 8; n++) {
                int col = wc + n * 16 + lr;
                bf16x4 pk;
#pragma unroll
                for (int r = 0; r < 4; r++) {
                    int row = wr + m * 16 + rq + r;
                    float val = RATIO * (expf(acc[m][n][r] * DN - diag_s[row] - kmx) + EPSK);
                    pk[r] = (bf16_t)val;
                    sj[n] += val;
                }
                *(bf16x4*)&outp[((size_t)bh * MF + col) * 4096 + n0 + wr + m * 16 + rq] = pk;
            }
        }
#pragma unroll
        for (int n = 0; n < 8; n++) {
            sj[n] += __shfl_xor(sj[n], 16);
            sj[n] += __shfl_xor(sj[n], 32);
        }
        if (wv < 2 && ln < 16) {
#pragma unroll
            for (int n = 0; n < 8; n++) ksp_s[wc + n * 16 + ln] = sj[n];
        }
        __syncthreads();
        if (wv >= 2 && ln < 16) {
#pragma unroll
            for (int n = 0; n < 8; n++) ksp_s[wc + n * 16 + ln] += sj[n];
        }
        __syncthreads();
        ksum_part[(size_t)bid * 256 + tid] = ksp_s[tid];
    }
}

__global__ __launch_bounds__(64) void kmax_reduce_kernel(const float* __restrict__ part,
                                                         float* __restrict__ kmax) {
    int bh = blockIdx.x, tid = threadIdx.x;
    float v = (tid < 32) ? part[bh * 32 + tid] : -1e30f;
#pragma unroll
    for (int off = 16; off > 0; off >>= 1) v = fmaxf(v, __shfl_down(v, off));
    if (tid == 0) kmax[bh] = v;
}

// ---------------- ctx split-K GEMM ----------------
__global__ __launch_bounds__(256) void ctx_gemm(const bf16_t* __restrict__ KPt,
                                                const bf16_t* __restrict__ Vt,
                                                float* __restrict__ part) {
    int bh = blockIdx.y;
    int mtile = blockIdx.x & 1, kc = blockIdx.x >> 1;
    int m0 = mtile * 128, nb = kc * 512;
    int tid = threadIdx.x, wv = tid >> 6, ln = tid & 63;
    __shared__ __attribute__((aligned(16))) bf16_t As[128 * 64];
    __shared__ __attribute__((aligned(16))) bf16_t Bs[64 * 64];
    int lrow8 = ln >> 3;
    int lchunk = ((ln & 7) ^ (lrow8 & 7)) * 8;
    int lr = ln & 15, kg = ln >> 4, rq = kg * 4;
    int wr = wv * 32;
    f32x4v acc[2][4] = {};
    for (int kt = 0; kt < 8; kt++) {
        int noff = nb + kt * 64;
        __syncthreads();
#pragma unroll
        for (int i = 0; i < 4; i++) {
            int e = wv * 4 + i;
            __builtin_amdgcn_global_load_lds(
                AS1(KPt + ((size_t)bh * MF + m0 + e * 8 + lrow8) * 4096 + noff + lchunk),
                AS3(&As[e * 512]), 16, 0, 0);
        }
#pragma unroll
        for (int i = 0; i < 2; i++) {
            int e = wv * 2 + i;
            __builtin_amdgcn_global_load_lds(
                AS1(Vt + ((size_t)bh * 64 + e * 8 + lrow8) * 4096 + noff + lchunk),
                AS3(&Bs[e * 512]), 16, 0, 0);
        }
        __syncthreads();
#pragma unroll
        for (int ks = 0; ks < 2; ks++) {
            int g = ks * 4 + kg;
            bf16x8 af[2], bfv[4];
#pragma unroll
            for (int m = 0; m < 2; m++) {
                int row = wr + m * 16 + lr;
                af[m] = *(const bf16x8*)&As[row * 64 + ((g ^ (row & 7)) * 8)];
            }
#pragma unroll
            for (int n = 0; n < 4; n++) {
                int row = n * 16 + lr;
                bfv[n] = *(const bf16x8*)&Bs[row * 64 + ((g ^ (row & 7)) * 8)];
            }
#pragma unroll
            for (int m = 0; m < 2; m++)
#pragma unroll
                for (int n = 0; n < 4; n++)
                    acc[m][n] = __builtin_amdgcn_mfma_f32_16x16x32_bf16(af[m], bfv[n], acc[m][n], 0, 0, 0);
        }
    }
#pragma unroll
    for (int m = 0; m < 2; m++)
#pragma unroll
        for (int n = 0; n < 4; n++)
#pragma unroll
            for (int r = 0; r < 4; r++)
                part[((size_t)(kc * 16 + bh) * MF + m0 + wr + m * 16 + rq + r) * 64 + n * 16 + lr] =
                    acc[m][n][r];
}

// ---------------- ctx reduce -> ctx_t[bh][d][m] bf16; + ksum reduce ----------------
__global__ __launch_bounds__(256) void ctx_reduce_kernel(const float* __restrict__ part,
                                                         const float* __restrict__ ksum_part,
                                                         bf16_t* __restrict__ ctx_t,
                                                         float* __restrict__ ksum) {
    int bh = blockIdx.x;
    for (int it = 0; it < 64; it++) {
        int idx = it * 256 + threadIdx.x;
        int m = idx >> 6, d = idx & 63;
        float s = 0.f;
#pragma unroll
        for (int kc = 0; kc < 8; kc++)
            s += part[(size_t)(kc * 16 + bh) * 16384 + idx];
        ctx_t[((size_t)bh * 64 + d) * MF + m] = (bf16_t)s;
    }
    {
        float s = 0.f;
#pragma unroll
        for (int t = 0; t < 32; t++)
            s += ksum_part[((size_t)bh * 32 + t) * 256 + threadIdx.x];
        ksum[bh * MF + threadIdx.x] = s;
    }
}

// ---------------- fused Q-side: q-features + dinv + (qp@ctx)*dinv -> abuf ----------------
__global__ __launch_bounds__(256) void qfused_kernel(const bf16_t* __restrict__ qkvb,
                                                     const bf16_t* __restrict__ projb,
                                                     const bf16_t* __restrict__ ctx_t,
                                                     const float* __restrict__ ksumb,
                                                     bf16_t* __restrict__ abuf) {
    int bid = blockIdx.x;
    int bh = bid >> 5, tile = bid & 31;
    int b = bh >> 3, hh = bh & 7;
    int tid = threadIdx.x, wv = tid >> 6, ln = tid & 63;
    __shared__ __attribute__((aligned(16))) bf16_t Qs[128 * 64];
    __shared__ __attribute__((aligned(16))) bf16_t Ps[256 * 64];
    __shared__ __attribute__((aligned(16))) bf16_t Cs[64 * 256];
    __shared__ float diag_s[128];
    __shared__ float rmx_s[2][128];
    __shared__ float dsum_s[128];
    int n0 = tile * 128;
    int lrow8 = ln >> 3;
    int lchunk = ((ln & 7) ^ (lrow8 & 7)) * 8;
#pragma unroll
    for (int i = 0; i < 4; i++) {
        int e = wv * 4 + i;
        size_t src = (size_t)(b * SEQN + n0 + e * 8 + lrow8) * 1024 + hh * 64 + lchunk;
        __builtin_amdgcn_global_load_lds(AS1(qkvb + src), AS3(&Qs[e * 512]), 16, 0, 0);
    }
#pragma unroll
    for (int i = 0; i < 8; i++) {
        int e = wv * 8 + i;
        size_t src = (size_t)(e * 8 + lrow8) * 64 + lchunk;
        __builtin_amdgcn_global_load_lds(AS1(projb + src), AS3(&Ps[e * 512]), 16, 0, 0);
    }
#pragma unroll
    for (int i = 0; i < 8; i++) {
        int c = i * 256 + tid;
        int cb = i * 256 + (tid & ~63);
        int crow = c >> 5, cch = c & 31;
        size_t src = ((size_t)bh * 64 + crow) * 256 + (size_t)(cch ^ (crow & 7)) * 8;
        __builtin_amdgcn_global_load_lds(AS1(ctx_t + src), AS3(Cs + (size_t)cb * 8), 16, 0, 0);
    }
    int wr = (wv >> 1) * 64, wc = (wv & 1) * 128;
    int lr = ln & 15, kg = ln >> 4, rq = kg * 4;
    float ksum_r[8];
#pragma unroll
    for (int n = 0; n < 8; n++) ksum_r[n] = ksumb[bh * MF + wc + n * 16 + lr];
    __syncthreads();
    if (tid < 128) {
        float s = 0.f;
#pragma unroll
        for (int c = 0; c < 8; c++) {
            bf16x8 v = *(const bf16x8*)&Qs[tid * 64 + ((c ^ (tid & 7)) * 8)];
#pragma unroll
            for (int j = 0; j < 8; j++) { float f = (float)v[j]; s += f * f; }
        }
        diag_s[tid] = s * (0.5f * DN * DN);
    }
    f32x4v acc[4][8] = {};
#pragma unroll
    for (int ks = 0; ks < 2; ks++) {
        int g = ks * 4 + kg;
        bf16x8 af[4], bfv[8];
#pragma unroll
        for (int m = 0; m < 4; m++) {
            int row = wr + m * 16 + lr;
            af[m] = *(const bf16x8*)&Qs[row * 64 + ((g ^ (row & 7)) * 8)];
        }
#pragma unroll
        for (int n = 0; n < 8; n++) {
            int row = wc + n * 16 + lr;
            bfv[n] = *(const bf16x8*)&Ps[row * 64 + ((g ^ (row & 7)) * 8)];
        }
#pragma unroll
        for (int m = 0; m < 4; m++)
#pragma unroll
            for (int n = 0; n < 8; n++)
                acc[m][n] = __builtin_amdgcn_mfma_f32_16x16x32_bf16(af[m], bfv[n], acc[m][n], 0, 0, 0);
    }
    float pmax[4][4];
#pragma unroll
    for (int m = 0; m < 4; m++)
#pragma unroll
        for (int r = 0; r < 4; r++) {
            float mx = acc[m][0][r];
#pragma unroll
            for (int n = 1; n < 8; n++) mx = fmaxf(mx, acc[m][n][r]);
#pragma unroll
            for (int mask = 1; mask < 16; mask <<= 1)
                mx = fmaxf(mx, __shfl_xor(mx, mask));
            pmax[m][r] = mx;
        }
    if (lr == 0) {
#pragma unroll
        for (int m = 0; m < 4; m++)
#pragma unroll
            for (int r = 0; r < 4; r++)
                rmx_s[wv & 1][wr + m * 16 + rq + r] = pmax[m][r] * DN;
    }
    __syncthreads();
    float dsum_p[4][4];
#pragma unroll
    for (int m = 0; m < 4; m++) {
#pragma unroll
        for (int r = 0; r < 4; r++) {
            int row = wr + m * 16 + rq + r;
            float rm = fmaxf(rmx_s[0][row], rmx_s[1][row]);
            float dg = diag_s[row];
            float ds = 0.f;
#pragma unroll
            for (int n = 0; n < 8; n++) {
                float val = RATIO * (expf(acc[m][n][r] * DN - dg - rm) + EPSK);
                acc[m][n][r] = val;
                ds += val * ksum_r[n];
            }
            dsum_p[m][r] = ds;
        }
    }
#pragma unroll
    for (int m = 0; m < 4; m++)
#pragma unroll
        for (int r = 0; r < 4; r++) {
#pragma unroll
            for (int mask = 1; mask < 16; mask <<= 1)
                dsum_p[m][r] += __shfl_xor(dsum_p[m][r], mask);
        }
    if ((wv & 1) == 0 && lr == 0) {
#pragma unroll
        for (int m = 0; m < 4; m++)
#pragma unroll
            for (int r = 0; r < 4; r++)
                dsum_s[wr + m * 16 + rq + r] = dsum_p[m][r];
    }
    __syncthreads();
    if ((wv & 1) == 1 && lr == 0) {
#pragma unroll
        for (int m = 0; m < 4; m++)
#pragma unroll
            for (int r = 0; r < 4; r++) {
                int row = wr + m * 16 + rq + r;
                dsum_s[row] = 1.0f / (dsum_s[row] + dsum_p[m][r]);
            }
    }
    __syncthreads();
    f32x4v acc_o[4][2] = {};
#pragma unroll
    for (int h = 0; h < 2; h++) {
        if ((wv & 1) == h) {
#pragma unroll
            for (int m = 0; m < 4; m++)
#pragma unroll
                for (int n = 0; n < 8; n++)
#pragma unroll
                    for (int r = 0; r < 4; r++) {
                        int row = wr + m * 16 + rq + r;
                        int ml = n * 16 + lr;
                        Ps[row * 128 + (((ml >> 3) ^ (row & 7)) * 8) + (ml & 7)] =
                            (bf16_t)acc[m][n][r];
                    }
        }
        __syncthreads();
#pragma unroll
        for (int ku = 0; ku < 4; ku++) {
            int g = ku * 4 + kg;
            bf16x8 af[4], bfv[2];
#pragma unroll
            for (int m = 0; m < 4; m++) {
                int row = wr + m * 16 + lr;
                af[m] = *(const bf16x8*)&Ps[row * 128 + ((g ^ (row & 7)) * 8)];
            }
#pragma unroll
            for (int n = 0; n < 2; n++) {
                int rowd = (wv & 1) * 32 + n * 16 + lr;
                int ch = (h * 16 + g) ^ (rowd & 7);
                bfv[n] = *(const bf16x8*)&Cs[(rowd * 32 + ch) * 8];
            }
#pragma unroll
            for (int m = 0; m < 4; m++)
#pragma unroll
                for (int n = 0; n < 2; n++)
                    acc_o[m][n] = __builtin_amdgcn_mfma_f32_16x16x32_bf16(af[m], bfv[n], acc_o[m][n], 0, 0, 0);
        }
        __syncthreads();
    }
#pragma unroll
    for (int m = 0; m < 4; m++) {
#pragma unroll
        for (int r = 0; r < 4; r++) {
            int rowl = wr + m * 16 + rq + r;
            float di = dsum_s[rowl];
            size_t obase = ((size_t)(b * SEQN + n0 + rowl)) * DMODEL + hh * 64;
#pragma unroll
            for (int n = 0; n < 2; n++) {
                int d = (wv & 1) * 32 + n * 16 + lr;
                abuf[obase + d] = (bf16_t)(acc_o[m][n][r] * di);
            }
        }
    }
}

extern "C" void kernel_launch(void* const* d_in, const int* in_sizes, int n_in,
                              void* d_out, int out_size, void* d_ws, size_t ws_size,
                              hipStream_t stream) {
    const float* x     = (const float*)d_in[0];
    const float* proj  = (const float*)d_in[1];
    const float* ln1_g = (const float*)d_in[2];
    const float* ln1_b = (const float*)d_in[3];
    const float* Wqkv  = (const float*)d_in[4];
    const float* bqkv  = (const float*)d_in[5];
    const float* Wo    = (const float*)d_in[6];
    const float* bo    = (const float*)d_in[7];
    const float* ln2_g = (const float*)d_in[8];
    const float* ln2_b = (const float*)d_in[9];
    const float* Wff1  = (const float*)d_in[10];
    const float* bff1  = (const float*)d_in[11];
    const float* Wff2  = (const float*)d_in[12];
    const float* bff2  = (const float*)d_in[13];

    float* h = (float*)d_out;
    char* ws = (char*)d_ws;
    bf16_t* KPt   = (bf16_t*)(ws);
    bf16_t* ybf   = (bf16_t*)(ws);               // [0, 8Mi)   (dead when KPt live)
    bf16_t* pWo   = (bf16_t*)(ws + 8388608);     // [8Mi,16Mi)
    bf16_t* pFF2  = (bf16_t*)(ws + 16777216);    // [16Mi,24Mi)
    bf16_t* qkvb  = (bf16_t*)(ws + 33554432);
    bf16_t* abufb = (bf16_t*)(ws + 50331648);
    float*  ctx_part  = (float*)(ws + 58720256);
    float*  ksum_part = (float*)(ws + 67108864);
    bf16_t* ffmidb    = (bf16_t*)(ws + 50331648);
    bf16_t* Vt    = (bf16_t*)(ws + 83886080);
    bf16_t* projb = (bf16_t*)(ws + 92274688);
    bf16_t* ctx_t = (bf16_t*)(ws + 92405760);
    float*  ksumb = (float*)(ws + 92930048);
    float*  kpart = (float*)(ws + 92946432);
    float*  kmaxb = (float*)(ws + 92948480);
    bf16_t* wbase = (bf16_t*)(ws + 93061120);
    const size_t WSLOT = 3407872;
    bool hoist = ws_size >= (size_t)93061120 + 4 * 6815744;

    hipMemcpyAsync(h, x, (size_t)NROWS * DMODEL * sizeof(float),
                   hipMemcpyDeviceToDevice, stream);
    pconv_kernel<<<64, 256, 0, stream>>>(proj, projb);
    if (hoist)
        wconv_all<<<dim3(3072, 4), 256, 0, stream>>>(Wqkv, Wo, Wff1, Wff2, wbase);

    for (int i = 0; i < DEPTH; i++) {
        const bf16_t* pj = projb + (size_t)i * MF * DH;
        if (!hoist)
            wconv_all<<<dim3(3072, 1), 256, 0, stream>>>(
                Wqkv + (size_t)i * 786432, Wo + (size_t)i * 262144,
                Wff1 + (size_t)i * 1048576, Wff2 + (size_t)i * 1048576, wbase);
        bf16_t* wl = wbase + (hoist ? (size_t)i * WSLOT : 0);
        bf16_t* wq_t = wl;
        bf16_t* wo_t = wl + 786432;
        bf16_t* w1_t = wl + 1048576;
        bf16_t* w2_t = wl + 2097152;

        if (i == 0)
            ln_kernel<<<NROWS, 256, 0, stream>>>(h, ln1_g, ln1_b, ybf);
        else
            ln_add_kernel<<<NROWS, 256, 0, stream>>>(h, pFF2, ln1_g + i * DMODEL,
                                                     ln1_b + i * DMODEL, ybf);
        gemm_pipe<128, 64, 32, 4, 0, 0, 0, 0, 1>
            <<<dim3(1536 / 64, NROWS / 128), 256, 0, stream>>>(
            ybf, wq_t, bqkv + i * 1536, nullptr, qkvb, Vt, 1536, 512);
        feat_kernel<1><<<512, 256, 0, stream>>>(qkvb, pj, nullptr, nullptr, kpart, nullptr);
        kmax_reduce_kernel<<<16, 64, 0, stream>>>(kpart, kmaxb);
        feat_kernel<2><<<512, 256, 0, stream>>>(qkvb, pj, kmaxb, KPt, nullptr, ksum_part);
        ctx_gemm<<<dim3(16, 16), 256, 0, stream>>>(KPt, Vt, ctx_part);
        ctx_reduce_kernel<<<16, 256, 0, stream>>>(ctx_part, ksum_part, ctx_t, ksumb);
        qfused_kernel<<<512, 256, 0, stream>>>(qkvb, pj, ctx_t, ksumb, abufb);
        gemm_pipe<128, 64, 32, 4, 0, 0, 0, 1, 0>
            <<<dim3(512 / 64, NROWS / 128), 256, 0, stream>>>(
            abufb, wo_t, bo + i * DMODEL, nullptr, pWo, nullptr, 512, 512);

        ln_add_kernel<<<NROWS, 256, 0, stream>>>(h, pWo, ln2_g + i * DMODEL,
                                                 ln2_b + i * DMODEL, ybf);
        gemm_pipe<128, 64, 32, 4, 1, 0, 0, 1, 0>
            <<<dim3(2048 / 64, NROWS / 128), 256, 0, stream>>>(
            ybf, w1_t, bff1 + i * FFD, nullptr, ffmidb, nullptr, 2048, 512);
        gemm_pipe<128, 64, 32, 4, 0, 0, 0, 1, 0>
            <<<dim3(512 / 64, NROWS / 128), 256, 0, stream>>>(
            ffmidb, w2_t, bff2 + i * DMODEL, nullptr, pFF2, nullptr, 512, 2048);
    }
    add_kernel<<<4096, 256, 0, stream>>>(h, pFF2);
}

// Round 15
// 868.778 us; speedup vs baseline: 1.0353x; 1.0353x over previous
//
#include <hip/hip_runtime.h>
#include <math.h>

#define DEPTH 4
#define DMODEL 512
#define DH 64
#define MF 256
#define FFD 2048
#define SEQN 4096
#define NROWS 8192

typedef __bf16 bf16_t;
typedef bf16_t bf16x8 __attribute__((ext_vector_type(8)));
typedef bf16_t bf16x4 __attribute__((ext_vector_type(4)));
typedef bf16_t bf16x2 __attribute__((ext_vector_type(2)));
typedef float f32x4v __attribute__((ext_vector_type(4)));

static constexpr float DN = 0.35355339059327373f;   // 64^-0.25
static constexpr float RATIO = 0.0625f;             // 256^-0.5
static constexpr float EPSK = 1e-4f;

__device__ __forceinline__ float gelu_exact(float x) {
    return 0.5f * x * (1.0f + erff(x * 0.70710678118654752f));
}

#define AS1(p) ((const __attribute__((address_space(1))) void*)(p))
#define AS3(p) ((__attribute__((address_space(3))) void*)(p))

template <int N> __device__ __forceinline__ void wait_vmcnt() {
    if constexpr (N == 0) asm volatile("s_waitcnt vmcnt(0)" ::: "memory");
    else if constexpr (N == 1) asm volatile("s_waitcnt vmcnt(1)" ::: "memory");
    else if constexpr (N == 2) asm volatile("s_waitcnt vmcnt(2)" ::: "memory");
    else if constexpr (N == 3) asm volatile("s_waitcnt vmcnt(3)" ::: "memory");
    else if constexpr (N == 4) asm volatile("s_waitcnt vmcnt(4)" ::: "memory");
    else if constexpr (N == 5) asm volatile("s_waitcnt vmcnt(5)" ::: "memory");
    else if constexpr (N == 6) asm volatile("s_waitcnt vmcnt(6)" ::: "memory");
    else if constexpr (N == 8) asm volatile("s_waitcnt vmcnt(8)" ::: "memory");
    else asm volatile("s_waitcnt vmcnt(12)" ::: "memory");
}

// ---------------- LayerNorm -> bf16 (no residual) ----------------
__global__ __launch_bounds__(256) void ln_kernel(const float* __restrict__ h,
                                                 const float* __restrict__ g,
                                                 const float* __restrict__ b,
                                                 bf16_t* __restrict__ y) {
    int row = blockIdx.x, tid = threadIdx.x;
    const float* hr = h + (size_t)row * DMODEL;
    float v0 = hr[tid], v1 = hr[tid + 256];
    __shared__ float s_sum[256], s_sq[256];
    s_sum[tid] = v0 + v1;
    s_sq[tid] = v0 * v0 + v1 * v1;
    __syncthreads();
    for (int off = 128; off > 0; off >>= 1) {
        if (tid < off) { s_sum[tid] += s_sum[tid + off]; s_sq[tid] += s_sq[tid + off]; }
        __syncthreads();
    }
    float mu = s_sum[0] * (1.0f / DMODEL);
    float var = s_sq[0] * (1.0f / DMODEL) - mu * mu;
    float rstd = rsqrtf(var + 1e-5f);
    bf16_t* yr = y + (size_t)row * DMODEL;
    yr[tid]       = (bf16_t)((v0 - mu) * rstd * g[tid] + b[tid]);
    yr[tid + 256] = (bf16_t)((v1 - mu) * rstd * g[tid + 256] + b[tid + 256]);
}

// ---------------- fused: h += P (bf16); LayerNorm(h) -> bf16; h written back ----------------
__global__ __launch_bounds__(256) void ln_add_kernel(float* __restrict__ h,
                                                     const bf16_t* __restrict__ p,
                                                     const float* __restrict__ g,
                                                     const float* __restrict__ b,
                                                     bf16_t* __restrict__ y) {
    int row = blockIdx.x, tid = threadIdx.x;
    float* hr = h + (size_t)row * DMODEL;
    const bf16_t* pr = p + (size_t)row * DMODEL;
    float2 hv = *(const float2*)(hr + 2 * tid);
    bf16x2 pv = *(const bf16x2*)(pr + 2 * tid);
    float v0 = hv.x + (float)pv[0];
    float v1 = hv.y + (float)pv[1];
    float2 outv; outv.x = v0; outv.y = v1;
    *(float2*)(hr + 2 * tid) = outv;
    __shared__ float s_sum[256], s_sq[256];
    s_sum[tid] = v0 + v1;
    s_sq[tid] = v0 * v0 + v1 * v1;
    __syncthreads();
    for (int off = 128; off > 0; off >>= 1) {
        if (tid < off) { s_sum[tid] += s_sum[tid + off]; s_sq[tid] += s_sq[tid + off]; }
        __syncthreads();
    }
    float mu = s_sum[0] * (1.0f / DMODEL);
    float var = s_sq[0] * (1.0f / DMODEL) - mu * mu;
    float rstd = rsqrtf(var + 1e-5f);
    bf16x2 ov;
    ov[0] = (bf16_t)((v0 - mu) * rstd * g[2 * tid] + b[2 * tid]);
    ov[1] = (bf16_t)((v1 - mu) * rstd * g[2 * tid + 1] + b[2 * tid + 1]);
    *(bf16x2*)(y + (size_t)row * DMODEL + 2 * tid) = ov;
}

// ---------------- tail: h += P (bf16) ----------------
__global__ __launch_bounds__(256) void add_kernel(float* __restrict__ h,
                                                  const bf16_t* __restrict__ p) {
    size_t i = ((size_t)blockIdx.x * 256 + threadIdx.x) * 4;
    float4 hv = *(const float4*)(h + i);
    bf16x4 pv = *(const bf16x4*)(p + i);
    hv.x += (float)pv[0]; hv.y += (float)pv[1];
    hv.z += (float)pv[2]; hv.w += (float)pv[3];
    *(float4*)(h + i) = hv;
}

// ---------------- weight transpose+convert; blockIdx.y = layer offset ----------------
__global__ __launch_bounds__(256) void wconv_all(const float* __restrict__ Wqkv,
                                                 const float* __restrict__ Wo,
                                                 const float* __restrict__ Wff1,
                                                 const float* __restrict__ Wff2,
                                                 bf16_t* __restrict__ wslot) {
    __shared__ float t[32][33];
    int layer = blockIdx.y;
    int bid = blockIdx.x;
    const float* W; bf16_t* Wt; int K, N, nx, lb;
    bf16_t* slot = wslot + (size_t)layer * 3407872;
    if (bid < 768)       { W = Wqkv + (size_t)layer * 786432;  Wt = slot;           K = 512;  N = 1536; nx = 48; lb = bid; }
    else if (bid < 1024) { W = Wo   + (size_t)layer * 262144;  Wt = slot + 786432;  K = 512;  N = 512;  nx = 16; lb = bid - 768; }
    else if (bid < 2048) { W = Wff1 + (size_t)layer * 1048576; Wt = slot + 1048576; K = 512;  N = 2048; nx = 64; lb = bid - 1024; }
    else                 { W = Wff2 + (size_t)layer * 1048576; Wt = slot + 2097152; K = 2048; N = 512;  nx = 16; lb = bid - 2048; }
    int n0 = (lb % nx) * 32, k0 = (lb / nx) * 32;
    int tx = threadIdx.x & 31, ty = threadIdx.x >> 5;
#pragma unroll
    for (int i = 0; i < 32; i += 8)
        t[ty + i][tx] = W[(size_t)(k0 + ty + i) * N + n0 + tx];
    __syncthreads();
#pragma unroll
    for (int i = 0; i < 32; i += 8)
        Wt[(size_t)(n0 + ty + i) * K + k0 + tx] = (bf16_t)t[tx][ty + i];
}

// ---------------- proj -> bf16 ----------------
__global__ __launch_bounds__(256) void pconv_kernel(const float* __restrict__ proj,
                                                    bf16_t* __restrict__ projb) {
    int i = (blockIdx.x * 256 + threadIdx.x) * 4;
    float4 v = *(const float4*)(proj + i);
    bf16x4 o;
    o[0] = (bf16_t)v.x; o[1] = (bf16_t)v.y; o[2] = (bf16_t)v.z; o[3] = (bf16_t)v.w;
    *(bf16x4*)(projb + i) = o;
}

// ---------------- 128x64 BK=32 P=3 pipelined MFMA GEMM, hoisted addressing ----------------
template <int BM, int BN, int BK, int P, int ACT, int RES, int WF, int WB, int QKVE>
__global__ __launch_bounds__(256) void gemm_pipe(const bf16_t* __restrict__ A,
                                                 const bf16_t* __restrict__ Bt,
                                                 const float* __restrict__ bias,
                                                 float* __restrict__ Cf,
                                                 bf16_t* __restrict__ Cb,
                                                 bf16_t* __restrict__ Vt,
                                                 int N, int K) {
    static_assert(BK == 32, "BK fixed at 32 (KS==1)");
    constexpr int MR = BM / 2 / 16;
    constexpr int NR = BN / 2 / 16;
    constexpr int CH = BK / 8;
    constexpr int SWZ = CH - 1;
    constexpr int TILE = (BM + BN) * BK;
    constexpr int L = TILE / 8 / 256;
    __shared__ __attribute__((aligned(16))) bf16_t smem[P * TILE];
    int tid = threadIdx.x;
    int wv = tid >> 6, ln = tid & 63;
    int gx = gridDim.x;
    int lin = blockIdx.y * gx + blockIdx.x;
    int per = (gx * gridDim.y) >> 3;
    int orig = (lin & 7) * per + (lin >> 3);
    int m0 = (orig / gx) * BM, n0 = (orig % gx) * BN;
    int wr = (wv >> 1) * (MR * 16), wc = (wv & 1) * (NR * 16);
    int lr = ln & 15, kq8 = ln >> 4;
    int nsteps = K / BK;

    const bf16_t* gsrc[L];
    int ldst[L];
#pragma unroll
    for (int i = 0; i < L; i++) {
        int c = i * 256 + tid;
        int cb = i * 256 + (tid & ~63);
        bool inA = (c < BM * CH);
        int cc = inA ? c : c - BM * CH;
        int row = cc / CH, ch = cc % CH;
        const bf16_t* mat = inA ? A : Bt;
        int r0 = inA ? m0 : n0;
        int chs = ch ^ ((row ^ (row >> 2)) & SWZ);
        gsrc[i] = mat + (size_t)(r0 + row) * K + chs * 8;
        ldst[i] = cb * 8;
    }
    auto stage = [&](int tile, int sb) {
        int k0 = tile * BK;
        bf16_t* dst = smem + sb * TILE;
#pragma unroll
        for (int i = 0; i < L; i++)
            __builtin_amdgcn_global_load_lds(AS1(gsrc[i] + k0), AS3(dst + ldst[i]), 16, 0, 0);
    };

    int aoff[MR], boff[NR];
#pragma unroll
    for (int m = 0; m < MR; m++) {
        int row = wr + m * 16 + lr;
        aoff[m] = (row * CH + (kq8 ^ ((row ^ (row >> 2)) & SWZ))) * 8;
    }
#pragma unroll
    for (int n = 0; n < NR; n++) {
        int row = wc + n * 16 + lr;
        boff[n] = BM * BK + (row * CH + (kq8 ^ ((row ^ (row >> 2)) & SWZ))) * 8;
    }

    f32x4v acc[MR][NR] = {};
#pragma unroll
    for (int p = 0; p < P - 1; ++p) stage(p, p);

    int cur = 0;
    for (int t = 0; t < nsteps; ++t) {
        int rem = nsteps - 1 - t;
        if (rem >= P - 2) wait_vmcnt<(P - 2) * L>();
        else if constexpr (P >= 4) {
            if (rem == 1) wait_vmcnt<L>(); else wait_vmcnt<0>();
        } else wait_vmcnt<0>();
        __builtin_amdgcn_s_barrier();
        asm volatile("" ::: "memory");
        if (t + P - 1 < nsteps) {
            int sb = cur - 1; if (sb < 0) sb = P - 1;
            stage(t + P - 1, sb);
        }
        const bf16_t* base = smem + cur * TILE;
        bf16x8 af[MR], bfr[NR];
#pragma unroll
        for (int m = 0; m < MR; m++) af[m] = *(const bf16x8*)&base[aoff[m]];
#pragma unroll
        for (int n = 0; n < NR; n++) bfr[n] = *(const bf16x8*)&base[boff[n]];
        __builtin_amdgcn_s_setprio(1);
#pragma unroll
        for (int m = 0; m < MR; m++)
#pragma unroll
            for (int n = 0; n < NR; n++)
                acc[m][n] = __builtin_amdgcn_mfma_f32_16x16x32_bf16(af[m], bfr[n], acc[m][n], 0, 0, 0);
        __builtin_amdgcn_s_setprio(0);
        cur = (cur + 1 == P) ? 0 : cur + 1;
    }
    int rq = (ln >> 4) * 4;
    if (WB || QKVE) {
        __syncthreads();
        bf16_t* T = smem;
        constexpr int S = BN + 8;
#pragma unroll
        for (int n = 0; n < NR; n++) {
            int col = wc + n * 16 + lr;
            float bcol = bias[n0 + col];
#pragma unroll
            for (int m = 0; m < MR; m++) {
#pragma unroll
                for (int r = 0; r < 4; r++) {
                    int row = wr + m * 16 + rq + r;
                    float v = acc[m][n][r] + bcol;
                    if (ACT == 1) v = gelu_exact(v);
                    int cs = (col & 7) | ((((col >> 3) ^ (row >> 3)) & (BN / 8 - 1)) << 3);
                    T[row * S + cs] = (bf16_t)v;
                }
            }
        }
        __syncthreads();
        if (!QKVE || n0 < 1024) {
            int ldc = QKVE ? 1024 : N;
#pragma unroll
            for (int i = 0; i < BM * BN / 8 / 256; i++) {
                int e = i * 2048 + tid * 8;
                int row = e / BN, c0 = e % BN;
                int ch = ((c0 >> 3) ^ (row >> 3)) & (BN / 8 - 1);
                bf16x8 v = *(const bf16x8*)&T[row * S + ch * 8];
                *(bf16x8*)&Cb[(size_t)(m0 + row) * ldc + n0 + c0] = v;
            }
        } else {
#pragma unroll
            for (int i = 0; i < BM * BN / 8 / 256; i++) {
                int u = i * 256 + tid;
                int d = u & (BN - 1), nb8 = (u / BN) * 8;
                bf16x8 v;
#pragma unroll
                for (int j = 0; j < 8; j++) {
                    int row = nb8 + j;
                    int cs = (d & 7) | ((((d >> 3) ^ (row >> 3)) & (BN / 8 - 1)) << 3);
                    v[j] = T[row * S + cs];
                }
                int gcol = n0 + d;
                int hh2 = (gcol >> 6) & 7, dd2 = gcol & 63;
                int grow = m0 + nb8;
                int bb = grow >> 12, nn = grow & 4095;
                *(bf16x8*)&Vt[(((size_t)bb * 8 + hh2) * 64 + dd2) * 4096 + nn] = v;
            }
        }
    } else {
#pragma unroll
        for (int n = 0; n < NR; n++) {
            int col = n0 + wc + n * 16 + lr;
            float bcol = bias[col];
#pragma unroll
            for (int m = 0; m < MR; m++) {
#pragma unroll
                for (int r = 0; r < 4; r++) {
                    int row = m0 + wr + m * 16 + rq + r;
                    float v = acc[m][n][r] + bcol;
                    if (ACT == 1) v = gelu_exact(v);
                    size_t idx = (size_t)row * N + col;
                    if (RES) Cf[idx] += v;
                    else Cf[idx] = v;
                }
            }
        }
    }
}

// ---------------- K-feature GEMM: dd[128n x 256m] per block, K=64 ----------------
// MODE 1 = K max pass (block max -> kpart); MODE 2 = exp pass (folds kpart itself)
template <int MODE>
__global__ __launch_bounds__(256) void feat_kernel(const bf16_t* __restrict__ qkvb,
                                                   const bf16_t* __restrict__ projb,
                                                   const float* __restrict__ kpart_in,
                                                   bf16_t* __restrict__ outp,
                                                   float* __restrict__ kpart,
                                                   float* __restrict__ ksum_part) {
    int bid = blockIdx.x;
    int bh = bid >> 5, tile = bid & 31;
    int b = bh >> 3, hh = bh & 7;
    int tid = threadIdx.x, wv = tid >> 6, ln = tid & 63;
    __shared__ __attribute__((aligned(16))) bf16_t As[128 * 64];
    __shared__ __attribute__((aligned(16))) bf16_t Bs[256 * 64];
    __shared__ float diag_s[128];
    __shared__ float red_s[256];
    __shared__ float ksp_s[256];
    int n0 = tile * 128;
    int qoff = 512 + hh * 64;
    int lrow8 = ln >> 3;
    int lchunk = ((ln & 7) ^ (lrow8 & 7)) * 8;
#pragma unroll
    for (int i = 0; i < 4; i++) {
        int e = wv * 4 + i;
        size_t src = (size_t)(b * SEQN + n0 + e * 8 + lrow8) * 1024 + qoff + lchunk;
        __builtin_amdgcn_global_load_lds(AS1(qkvb + src), AS3(&As[e * 512]), 16, 0, 0);
    }
#pragma unroll
    for (int i = 0; i < 8; i++) {
        int e = wv * 8 + i;
        size_t src = (size_t)(e * 8 + lrow8) * 64 + lchunk;
        __builtin_amdgcn_global_load_lds(AS1(projb + src), AS3(&Bs[e * 512]), 16, 0, 0);
    }
    __syncthreads();
    if (MODE == 2 && tid < 128) {
        float s = 0.f;
#pragma unroll
        for (int c = 0; c < 8; c++) {
            bf16x8 v = *(const bf16x8*)&As[tid * 64 + ((c ^ (tid & 7)) * 8)];
#pragma unroll
            for (int j = 0; j < 8; j++) { float f = (float)v[j]; s += f * f; }
        }
        diag_s[tid] = s * (0.5f * DN * DN);
    }
    int wr = (wv >> 1) * 64, wc = (wv & 1) * 128;
    int lr = ln & 15, kg = ln >> 4, rq = kg * 4;
    f32x4v acc[4][8] = {};
#pragma unroll
    for (int ks = 0; ks < 2; ks++) {
        int g = ks * 4 + kg;
        bf16x8 af[4], bfv[8];
#pragma unroll
        for (int m = 0; m < 4; m++) {
            int row = wr + m * 16 + lr;
            af[m] = *(const bf16x8*)&As[row * 64 + ((g ^ (row & 7)) * 8)];
        }
#pragma unroll
        for (int n = 0; n < 8; n++) {
            int row = wc + n * 16 + lr;
            bfv[n] = *(const bf16x8*)&Bs[row * 64 + ((g ^ (row & 7)) * 8)];
        }
#pragma unroll
        for (int m = 0; m < 4; m++)
#pragma unroll
            for (int n = 0; n < 8; n++)
                acc[m][n] = __builtin_amdgcn_mfma_f32_16x16x32_bf16(af[m], bfv[n], acc[m][n], 0, 0, 0);
    }
    if (MODE == 1) {
        float mx = -1e30f;
#pragma unroll
        for (int m = 0; m < 4; m++)
#pragma unroll
            for (int n = 0; n < 8; n++)
#pragma unroll
                for (int r = 0; r < 4; r++) mx = fmaxf(mx, acc[m][n][r]);
        red_s[tid] = mx * DN;
        __syncthreads();
        for (int off = 128; off > 0; off >>= 1) {
            if (tid < off) red_s[tid] = fmaxf(red_s[tid], red_s[tid + off]);
            __syncthreads();
        }
        if (tid == 0) kpart[bid] = red_s[0];
    } else {
        // fold this bh's 32 block-partials (L2-resident)
        float kmx = kpart_in[bh * 32];
#pragma unroll
        for (int j = 1; j < 32; j++) kmx = fmaxf(kmx, kpart_in[bh * 32 + j]);
        __syncthreads();   // diag_s visible
        float sj[8] = {};
#pragma unroll
        for (int m = 0; m < 4; m++) {
#pragma unroll
            for (int n = 0; n < 8; n++) {
                int col = wc + n * 16 + lr;
                bf16x4 pk;
#pragma unroll
                for (int r = 0; r < 4; r++) {
                    int row = wr + m * 16 + rq + r;
                    float val = RATIO * (expf(acc[m][n][r] * DN - diag_s[row] - kmx) + EPSK);
                    pk[r] = (bf16_t)val;
                    sj[n] += val;
                }
                *(bf16x4*)&outp[((size_t)bh * MF + col) * 4096 + n0 + wr + m * 16 + rq] = pk;
            }
        }
#pragma unroll
        for (int n = 0; n < 8; n++) {
            sj[n] += __shfl_xor(sj[n], 16);
            sj[n] += __shfl_xor(sj[n], 32);
        }
        if (wv < 2 && ln < 16) {
#pragma unroll
            for (int n = 0; n < 8; n++) ksp_s[wc + n * 16 + ln] = sj[n];
        }
        __syncthreads();
        if (wv >= 2 && ln < 16) {
#pragma unroll
            for (int n = 0; n < 8; n++) ksp_s[wc + n * 16 + ln] += sj[n];
        }
        __syncthreads();
        ksum_part[(size_t)bid * 256 + tid] = ksp_s[tid];
    }
}

// ---------------- ctx split-K GEMM ----------------
__global__ __launch_bounds__(256) void ctx_gemm(const bf16_t* __restrict__ KPt,
                                                const bf16_t* __restrict__ Vt,
                                                float* __restrict__ part) {
    int bh = blockIdx.y;
    int mtile = blockIdx.x & 1, kc = blockIdx.x >> 1;
    int m0 = mtile * 128, nb = kc * 512;
    int tid = threadIdx.x, wv = tid >> 6, ln = tid & 63;
    __shared__ __attribute__((aligned(16))) bf16_t As[128 * 64];
    __shared__ __attribute__((aligned(16))) bf16_t Bs[64 * 64];
    int lrow8 = ln >> 3;
    int lchunk = ((ln & 7) ^ (lrow8 & 7)) * 8;
    int lr = ln & 15, kg = ln >> 4, rq = kg * 4;
    int wr = wv * 32;
    f32x4v acc[2][4] = {};
    for (int kt = 0; kt < 8; kt++) {
        int noff = nb + kt * 64;
        __syncthreads();
#pragma unroll
        for (int i = 0; i < 4; i++) {
            int e = wv * 4 + i;
            __builtin_amdgcn_global_load_lds(
                AS1(KPt + ((size_t)bh * MF + m0 + e * 8 + lrow8) * 4096 + noff + lchunk),
                AS3(&As[e * 512]), 16, 0, 0);
        }
#pragma unroll
        for (int i = 0; i < 2; i++) {
            int e = wv * 2 + i;
            __builtin_amdgcn_global_load_lds(
                AS1(Vt + ((size_t)bh * 64 + e * 8 + lrow8) * 4096 + noff + lchunk),
                AS3(&Bs[e * 512]), 16, 0, 0);
        }
        __syncthreads();
#pragma unroll
        for (int ks = 0; ks < 2; ks++) {
            int g = ks * 4 + kg;
            bf16x8 af[2], bfv[4];
#pragma unroll
            for (int m = 0; m < 2; m++) {
                int row = wr + m * 16 + lr;
                af[m] = *(const bf16x8*)&As[row * 64 + ((g ^ (row & 7)) * 8)];
            }
#pragma unroll
            for (int n = 0; n < 4; n++) {
                int row = n * 16 + lr;
                bfv[n] = *(const bf16x8*)&Bs[row * 64 + ((g ^ (row & 7)) * 8)];
            }
#pragma unroll
            for (int m = 0; m < 2; m++)
#pragma unroll
                for (int n = 0; n < 4; n++)
                    acc[m][n] = __builtin_amdgcn_mfma_f32_16x16x32_bf16(af[m], bfv[n], acc[m][n], 0, 0, 0);
        }
    }
#pragma unroll
    for (int m = 0; m < 2; m++)
#pragma unroll
        for (int n = 0; n < 4; n++)
#pragma unroll
            for (int r = 0; r < 4; r++)
                part[((size_t)(kc * 16 + bh) * MF + m0 + wr + m * 16 + rq + r) * 64 + n * 16 + lr] =
                    acc[m][n][r];
}

// ---------------- ctx reduce -> ctx_t[bh][d][m] bf16; + ksum reduce ----------------
__global__ __launch_bounds__(256) void ctx_reduce_kernel(const float* __restrict__ part,
                                                         const float* __restrict__ ksum_part,
                                                         bf16_t* __restrict__ ctx_t,
                                                         float* __restrict__ ksum) {
    int bh = blockIdx.x;
    for (int it = 0; it < 64; it++) {
        int idx = it * 256 + threadIdx.x;
        int m = idx >> 6, d = idx & 63;
        float s = 0.f;
#pragma unroll
        for (int kc = 0; kc < 8; kc++)
            s += part[(size_t)(kc * 16 + bh) * 16384 + idx];
        ctx_t[((size_t)bh * 64 + d) * MF + m] = (bf16_t)s;
    }
    {
        float s = 0.f;
#pragma unroll
        for (int t = 0; t < 32; t++)
            s += ksum_part[((size_t)bh * 32 + t) * 256 + threadIdx.x];
        ksum[bh * MF + threadIdx.x] = s;
    }
}

// ---------------- fused Q-side: q-features + dinv + (qp@ctx)*dinv -> abuf ----------------
__global__ __launch_bounds__(256) void qfused_kernel(const bf16_t* __restrict__ qkvb,
                                                     const bf16_t* __restrict__ projb,
                                                     const bf16_t* __restrict__ ctx_t,
                                                     const float* __restrict__ ksumb,
                                                     bf16_t* __restrict__ abuf) {
    int bid = blockIdx.x;
    int bh = bid >> 5, tile = bid & 31;
    int b = bh >> 3, hh = bh & 7;
    int tid = threadIdx.x, wv = tid >> 6, ln = tid & 63;
    __shared__ __attribute__((aligned(16))) bf16_t Qs[128 * 64];
    __shared__ __attribute__((aligned(16))) bf16_t Ps[256 * 64];
    __shared__ __attribute__((aligned(16))) bf16_t Cs[64 * 256];
    __shared__ float diag_s[128];
    __shared__ float rmx_s[2][128];
    __shared__ float dsum_s[128];
    int n0 = tile * 128;
    int lrow8 = ln >> 3;
    int lchunk = ((ln & 7) ^ (lrow8 & 7)) * 8;
#pragma unroll
    for (int i = 0; i < 4; i++) {
        int e = wv * 4 + i;
        size_t src = (size_t)(b * SEQN + n0 + e * 8 + lrow8) * 1024 + hh * 64 + lchunk;
        __builtin_amdgcn_global_load_lds(AS1(qkvb + src), AS3(&Qs[e * 512]), 16, 0, 0);
    }
#pragma unroll
    for (int i = 0; i < 8; i++) {
        int e = wv * 8 + i;
        size_t src = (size_t)(e * 8 + lrow8) * 64 + lchunk;
        __builtin_amdgcn_global_load_lds(AS1(projb + src), AS3(&Ps[e * 512]), 16, 0, 0);
    }
#pragma unroll
    for (int i = 0; i < 8; i++) {
        int c = i * 256 + tid;
        int cb = i * 256 + (tid & ~63);
        int crow = c >> 5, cch = c & 31;
        size_t src = ((size_t)bh * 64 + crow) * 256 + (size_t)(cch ^ (crow & 7)) * 8;
        __builtin_amdgcn_global_load_lds(AS1(ctx_t + src), AS3(Cs + (size_t)cb * 8), 16, 0, 0);
    }
    int wr = (wv >> 1) * 64, wc = (wv & 1) * 128;
    int lr = ln & 15, kg = ln >> 4, rq = kg * 4;
    float ksum_r[8];
#pragma unroll
    for (int n = 0; n < 8; n++) ksum_r[n] = ksumb[bh * MF + wc + n * 16 + lr];
    __syncthreads();
    if (tid < 128) {
        float s = 0.f;
#pragma unroll
        for (int c = 0; c < 8; c++) {
            bf16x8 v = *(const bf16x8*)&Qs[tid * 64 + ((c ^ (tid & 7)) * 8)];
#pragma unroll
            for (int j = 0; j < 8; j++) { float f = (float)v[j]; s += f * f; }
        }
        diag_s[tid] = s * (0.5f * DN * DN);
    }
    f32x4v acc[4][8] = {};
#pragma unroll
    for (int ks = 0; ks < 2; ks++) {
        int g = ks * 4 + kg;
        bf16x8 af[4], bfv[8];
#pragma unroll
        for (int m = 0; m < 4; m++) {
            int row = wr + m * 16 + lr;
            af[m] = *(const bf16x8*)&Qs[row * 64 + ((g ^ (row & 7)) * 8)];
        }
#pragma unroll
        for (int n = 0; n < 8; n++) {
            int row = wc + n * 16 + lr;
            bfv[n] = *(const bf16x8*)&Ps[row * 64 + ((g ^ (row & 7)) * 8)];
        }
#pragma unroll
        for (int m = 0; m < 4; m++)
#pragma unroll
            for (int n = 0; n < 8; n++)
                acc[m][n] = __builtin_amdgcn_mfma_f32_16x16x32_bf16(af[m], bfv[n], acc[m][n], 0, 0, 0);
    }
    float pmax[4][4];
#pragma unroll
    for (int m = 0; m < 4; m++)
#pragma unroll
        for (int r = 0; r < 4; r++) {
            float mx = acc[m][0][r];
#pragma unroll
            for (int n = 1; n < 8; n++) mx = fmaxf(mx, acc[m][n][r]);
#pragma unroll
            for (int mask = 1; mask < 16; mask <<= 1)
                mx = fmaxf(mx, __shfl_xor(mx, mask));
            pmax[m][r] = mx;
        }
    if (lr == 0) {
#pragma unroll
        for (int m = 0; m < 4; m++)
#pragma unroll
            for (int r = 0; r < 4; r++)
                rmx_s[wv & 1][wr + m * 16 + rq + r] = pmax[m][r] * DN;
    }
    __syncthreads();
    float dsum_p[4][4];
#pragma unroll
    for (int m = 0; m < 4; m++) {
#pragma unroll
        for (int r = 0; r < 4; r++) {
            int row = wr + m * 16 + rq + r;
            float rm = fmaxf(rmx_s[0][row], rmx_s[1][row]);
            float dg = diag_s[row];
            float ds = 0.f;
#pragma unroll
            for (int n = 0; n < 8; n++) {
                float val = RATIO * (expf(acc[m][n][r] * DN - dg - rm) + EPSK);
                acc[m][n][r] = val;
                ds += val * ksum_r[n];
            }
            dsum_p[m][r] = ds;
        }
    }
#pragma unroll
    for (int m = 0; m < 4; m++)
#pragma unroll
        for (int r = 0; r < 4; r++) {
#pragma unroll
            for (int mask = 1; mask < 16; mask <<= 1)
                dsum_p[m][r] += __shfl_xor(dsum_p[m][r], mask);
        }
    if ((wv & 1) == 0 && lr == 0) {
#pragma unroll
        for (int m = 0; m < 4; m++)
#pragma unroll
            for (int r = 0; r < 4; r++)
                dsum_s[wr + m * 16 + rq + r] = dsum_p[m][r];
    }
    __syncthreads();
    if ((wv & 1) == 1 && lr == 0) {
#pragma unroll
        for (int m = 0; m < 4; m++)
#pragma unroll
            for (int r = 0; r < 4; r++) {
                int row = wr + m * 16 + rq + r;
                dsum_s[row] = 1.0f / (dsum_s[row] + dsum_p[m][r]);
            }
    }
    __syncthreads();
    f32x4v acc_o[4][2] = {};
#pragma unroll
    for (int h = 0; h < 2; h++) {
        if ((wv & 1) == h) {
#pragma unroll
            for (int m = 0; m < 4; m++)
#pragma unroll
                for (int n = 0; n < 8; n++)
#pragma unroll
                    for (int r = 0; r < 4; r++) {
                        int row = wr + m * 16 + rq + r;
                        int ml = n * 16 + lr;
                        Ps[row * 128 + (((ml >> 3) ^ (row & 7)) * 8) + (ml & 7)] =
                            (bf16_t)acc[m][n][r];
                    }
        }
        __syncthreads();
#pragma unroll
        for (int ku = 0; ku < 4; ku++) {
            int g = ku * 4 + kg;
            bf16x8 af[4], bfv[2];
#pragma unroll
            for (int m = 0; m < 4; m++) {
                int row = wr + m * 16 + lr;
                af[m] = *(const bf16x8*)&Ps[row * 128 + ((g ^ (row & 7)) * 8)];
            }
#pragma unroll
            for (int n = 0; n < 2; n++) {
                int rowd = (wv & 1) * 32 + n * 16 + lr;
                int ch = (h * 16 + g) ^ (rowd & 7);
                bfv[n] = *(const bf16x8*)&Cs[(rowd * 32 + ch) * 8];
            }
#pragma unroll
            for (int m = 0; m < 4; m++)
#pragma unroll
                for (int n = 0; n < 2; n++)
                    acc_o[m][n] = __builtin_amdgcn_mfma_f32_16x16x32_bf16(af[m], bfv[n], acc_o[m][n], 0, 0, 0);
        }
        __syncthreads();
    }
#pragma unroll
    for (int m = 0; m < 4; m++) {
#pragma unroll
        for (int r = 0; r < 4; r++) {
            int rowl = wr + m * 16 + rq + r;
            float di = dsum_s[rowl];
            size_t obase = ((size_t)(b * SEQN + n0 + rowl)) * DMODEL + hh * 64;
#pragma unroll
            for (int n = 0; n < 2; n++) {
                int d = (wv & 1) * 32 + n * 16 + lr;
                abuf[obase + d] = (bf16_t)(acc_o[m][n][r] * di);
            }
        }
    }
}

extern "C" void kernel_launch(void* const* d_in, const int* in_sizes, int n_in,
                              void* d_out, int out_size, void* d_ws, size_t ws_size,
                              hipStream_t stream) {
    const float* x     = (const float*)d_in[0];
    const float* proj  = (const float*)d_in[1];
    const float* ln1_g = (const float*)d_in[2];
    const float* ln1_b = (const float*)d_in[3];
    const float* Wqkv  = (const float*)d_in[4];
    const float* bqkv  = (const float*)d_in[5];
    const float* Wo    = (const float*)d_in[6];
    const float* bo    = (const float*)d_in[7];
    const float* ln2_g = (const float*)d_in[8];
    const float* ln2_b = (const float*)d_in[9];
    const float* Wff1  = (const float*)d_in[10];
    const float* bff1  = (const float*)d_in[11];
    const float* Wff2  = (const float*)d_in[12];
    const float* bff2  = (const float*)d_in[13];

    float* h = (float*)d_out;
    char* ws = (char*)d_ws;
    bf16_t* KPt   = (bf16_t*)(ws);
    bf16_t* ybf   = (bf16_t*)(ws);               // [0, 8Mi)   (dead when KPt live)
    bf16_t* pWo   = (bf16_t*)(ws + 8388608);     // [8Mi,16Mi)
    bf16_t* pFF2  = (bf16_t*)(ws + 16777216);    // [16Mi,24Mi)
    bf16_t* qkvb  = (bf16_t*)(ws + 33554432);
    bf16_t* abufb = (bf16_t*)(ws + 50331648);
    float*  ctx_part  = (float*)(ws + 58720256);
    float*  ksum_part = (float*)(ws + 67108864);
    bf16_t* ffmidb    = (bf16_t*)(ws + 50331648);
    bf16_t* Vt    = (bf16_t*)(ws + 83886080);
    bf16_t* projb = (bf16_t*)(ws + 92274688);
    bf16_t* ctx_t = (bf16_t*)(ws + 92405760);
    float*  ksumb = (float*)(ws + 92930048);
    float*  kpart = (float*)(ws + 92946432);
    bf16_t* wbase = (bf16_t*)(ws + 93061120);
    const size_t WSLOT = 3407872;
    bool hoist = ws_size >= (size_t)93061120 + 4 * 6815744;

    hipMemcpyAsync(h, x, (size_t)NROWS * DMODEL * sizeof(float),
                   hipMemcpyDeviceToDevice, stream);
    pconv_kernel<<<64, 256, 0, stream>>>(proj, projb);
    if (hoist)
        wconv_all<<<dim3(3072, 4), 256, 0, stream>>>(Wqkv, Wo, Wff1, Wff2, wbase);

    for (int i = 0; i < DEPTH; i++) {
        const bf16_t* pj = projb + (size_t)i * MF * DH;
        if (!hoist)
            wconv_all<<<dim3(3072, 1), 256, 0, stream>>>(
                Wqkv + (size_t)i * 786432, Wo + (size_t)i * 262144,
                Wff1 + (size_t)i * 1048576, Wff2 + (size_t)i * 1048576, wbase);
        bf16_t* wl = wbase + (hoist ? (size_t)i * WSLOT : 0);
        bf16_t* wq_t = wl;
        bf16_t* wo_t = wl + 786432;
        bf16_t* w1_t = wl + 1048576;
        bf16_t* w2_t = wl + 2097152;

        if (i == 0)
            ln_kernel<<<NROWS, 256, 0, stream>>>(h, ln1_g, ln1_b, ybf);
        else
            ln_add_kernel<<<NROWS, 256, 0, stream>>>(h, pFF2, ln1_g + i * DMODEL,
                                                     ln1_b + i * DMODEL, ybf);
        gemm_pipe<128, 64, 32, 3, 0, 0, 0, 0, 1>
            <<<dim3(1536 / 64, NROWS / 128), 256, 0, stream>>>(
            ybf, wq_t, bqkv + i * 1536, nullptr, qkvb, Vt, 1536, 512);
        feat_kernel<1><<<512, 256, 0, stream>>>(qkvb, pj, nullptr, nullptr, kpart, nullptr);
        feat_kernel<2><<<512, 256, 0, stream>>>(qkvb, pj, kpart, KPt, nullptr, ksum_part);
        ctx_gemm<<<dim3(16, 16), 256, 0, stream>>>(KPt, Vt, ctx_part);
        ctx_reduce_kernel<<<16, 256, 0, stream>>>(ctx_part, ksum_part, ctx_t, ksumb);
        qfused_kernel<<<512, 256, 0, stream>>>(qkvb, pj, ctx_t, ksumb, abufb);
        gemm_pipe<128, 64, 32, 3, 0, 0, 0, 1, 0>
            <<<dim3(512 / 64, NROWS / 128), 256, 0, stream>>>(
            abufb, wo_t, bo + i * DMODEL, nullptr, pWo, nullptr, 512, 512);

        ln_add_kernel<<<NROWS, 256, 0, stream>>>(h, pWo, ln2_g + i * DMODEL,
                                                 ln2_b + i * DMODEL, ybf);
        gemm_pipe<128, 64, 32, 3, 1, 0, 0, 1, 0>
            <<<dim3(2048 / 64, NROWS / 128), 256, 0, stream>>>(
            ybf, w1_t, bff1 + i * FFD, nullptr, ffmidb, nullptr, 2048, 512);
        gemm_pipe<128, 64, 32, 3, 0, 0, 0, 1, 0>
            <<<dim3(512 / 64, NROWS / 128), 256, 0, stream>>>(
            ffmidb, w2_t, bff2 + i * DMODEL, nullptr, pFF2, nullptr, 512, 2048);
    }
    add_kernel<<<4096, 256, 0, stream>>>(h, pFF2);
}

// Round 16
// 839.608 us; speedup vs baseline: 1.0712x; 1.0347x over previous
//
#include <hip/hip_runtime.h>
#include <math.h>

#define DEPTH 4
#define DMODEL 512
#define DH 64
#define MF 256
#define FFD 2048
#define SEQN 4096
#define NROWS 8192

typedef __bf16 bf16_t;
typedef bf16_t bf16x8 __attribute__((ext_vector_type(8)));
typedef bf16_t bf16x4 __attribute__((ext_vector_type(4)));
typedef bf16_t bf16x2 __attribute__((ext_vector_type(2)));
typedef float f32x4v __attribute__((ext_vector_type(4)));

static constexpr float DN = 0.35355339059327373f;   // 64^-0.25
static constexpr float RATIO = 0.0625f;             // 256^-0.5
static constexpr float EPSK = 1e-4f;

__device__ __forceinline__ float gelu_exact(float x) {
    return 0.5f * x * (1.0f + erff(x * 0.70710678118654752f));
}

#define AS1(p) ((const __attribute__((address_space(1))) void*)(p))
#define AS3(p) ((__attribute__((address_space(3))) void*)(p))

template <int N> __device__ __forceinline__ void wait_vmcnt() {
    if constexpr (N == 0) asm volatile("s_waitcnt vmcnt(0)" ::: "memory");
    else if constexpr (N == 1) asm volatile("s_waitcnt vmcnt(1)" ::: "memory");
    else if constexpr (N == 2) asm volatile("s_waitcnt vmcnt(2)" ::: "memory");
    else if constexpr (N == 3) asm volatile("s_waitcnt vmcnt(3)" ::: "memory");
    else if constexpr (N == 4) asm volatile("s_waitcnt vmcnt(4)" ::: "memory");
    else if constexpr (N == 5) asm volatile("s_waitcnt vmcnt(5)" ::: "memory");
    else if constexpr (N == 6) asm volatile("s_waitcnt vmcnt(6)" ::: "memory");
    else if constexpr (N == 8) asm volatile("s_waitcnt vmcnt(8)" ::: "memory");
    else asm volatile("s_waitcnt vmcnt(12)" ::: "memory");
}

// ---------------- LayerNorm -> bf16 (no residual) ----------------
__global__ __launch_bounds__(256) void ln_kernel(const float* __restrict__ h,
                                                 const float* __restrict__ g,
                                                 const float* __restrict__ b,
                                                 bf16_t* __restrict__ y) {
    int row = blockIdx.x, tid = threadIdx.x;
    const float* hr = h + (size_t)row * DMODEL;
    float v0 = hr[tid], v1 = hr[tid + 256];
    __shared__ float s_sum[256], s_sq[256];
    s_sum[tid] = v0 + v1;
    s_sq[tid] = v0 * v0 + v1 * v1;
    __syncthreads();
    for (int off = 128; off > 0; off >>= 1) {
        if (tid < off) { s_sum[tid] += s_sum[tid + off]; s_sq[tid] += s_sq[tid + off]; }
        __syncthreads();
    }
    float mu = s_sum[0] * (1.0f / DMODEL);
    float var = s_sq[0] * (1.0f / DMODEL) - mu * mu;
    float rstd = rsqrtf(var + 1e-5f);
    bf16_t* yr = y + (size_t)row * DMODEL;
    yr[tid]       = (bf16_t)((v0 - mu) * rstd * g[tid] + b[tid]);
    yr[tid + 256] = (bf16_t)((v1 - mu) * rstd * g[tid + 256] + b[tid + 256]);
}

// ---------------- fused: h += P (bf16); LayerNorm(h) -> bf16; h written back ----------------
__global__ __launch_bounds__(256) void ln_add_kernel(float* __restrict__ h,
                                                     const bf16_t* __restrict__ p,
                                                     const float* __restrict__ g,
                                                     const float* __restrict__ b,
                                                     bf16_t* __restrict__ y) {
    int row = blockIdx.x, tid = threadIdx.x;
    float* hr = h + (size_t)row * DMODEL;
    const bf16_t* pr = p + (size_t)row * DMODEL;
    float2 hv = *(const float2*)(hr + 2 * tid);
    bf16x2 pv = *(const bf16x2*)(pr + 2 * tid);
    float v0 = hv.x + (float)pv[0];
    float v1 = hv.y + (float)pv[1];
    float2 outv; outv.x = v0; outv.y = v1;
    *(float2*)(hr + 2 * tid) = outv;
    __shared__ float s_sum[256], s_sq[256];
    s_sum[tid] = v0 + v1;
    s_sq[tid] = v0 * v0 + v1 * v1;
    __syncthreads();
    for (int off = 128; off > 0; off >>= 1) {
        if (tid < off) { s_sum[tid] += s_sum[tid + off]; s_sq[tid] += s_sq[tid + off]; }
        __syncthreads();
    }
    float mu = s_sum[0] * (1.0f / DMODEL);
    float var = s_sq[0] * (1.0f / DMODEL) - mu * mu;
    float rstd = rsqrtf(var + 1e-5f);
    bf16x2 ov;
    ov[0] = (bf16_t)((v0 - mu) * rstd * g[2 * tid] + b[2 * tid]);
    ov[1] = (bf16_t)((v1 - mu) * rstd * g[2 * tid + 1] + b[2 * tid + 1]);
    *(bf16x2*)(y + (size_t)row * DMODEL + 2 * tid) = ov;
}

// ---------------- tail: h += P (bf16) ----------------
__global__ __launch_bounds__(256) void add_kernel(float* __restrict__ h,
                                                  const bf16_t* __restrict__ p) {
    size_t i = ((size_t)blockIdx.x * 256 + threadIdx.x) * 4;
    float4 hv = *(const float4*)(h + i);
    bf16x4 pv = *(const bf16x4*)(p + i);
    hv.x += (float)pv[0]; hv.y += (float)pv[1];
    hv.z += (float)pv[2]; hv.w += (float)pv[3];
    *(float4*)(h + i) = hv;
}

// ---------------- weight transpose+convert; blockIdx.y = layer offset ----------------
__global__ __launch_bounds__(256) void wconv_all(const float* __restrict__ Wqkv,
                                                 const float* __restrict__ Wo,
                                                 const float* __restrict__ Wff1,
                                                 const float* __restrict__ Wff2,
                                                 bf16_t* __restrict__ wslot) {
    __shared__ float t[32][33];
    int layer = blockIdx.y;
    int bid = blockIdx.x;
    const float* W; bf16_t* Wt; int K, N, nx, lb;
    bf16_t* slot = wslot + (size_t)layer * 3407872;
    if (bid < 768)       { W = Wqkv + (size_t)layer * 786432;  Wt = slot;           K = 512;  N = 1536; nx = 48; lb = bid; }
    else if (bid < 1024) { W = Wo   + (size_t)layer * 262144;  Wt = slot + 786432;  K = 512;  N = 512;  nx = 16; lb = bid - 768; }
    else if (bid < 2048) { W = Wff1 + (size_t)layer * 1048576; Wt = slot + 1048576; K = 512;  N = 2048; nx = 64; lb = bid - 1024; }
    else                 { W = Wff2 + (size_t)layer * 1048576; Wt = slot + 2097152; K = 2048; N = 512;  nx = 16; lb = bid - 2048; }
    int n0 = (lb % nx) * 32, k0 = (lb / nx) * 32;
    int tx = threadIdx.x & 31, ty = threadIdx.x >> 5;
#pragma unroll
    for (int i = 0; i < 32; i += 8)
        t[ty + i][tx] = W[(size_t)(k0 + ty + i) * N + n0 + tx];
    __syncthreads();
#pragma unroll
    for (int i = 0; i < 32; i += 8)
        Wt[(size_t)(n0 + ty + i) * K + k0 + tx] = (bf16_t)t[tx][ty + i];
}

// ---------------- proj -> bf16 ----------------
__global__ __launch_bounds__(256) void pconv_kernel(const float* __restrict__ proj,
                                                    bf16_t* __restrict__ projb) {
    int i = (blockIdx.x * 256 + threadIdx.x) * 4;
    float4 v = *(const float4*)(proj + i);
    bf16x4 o;
    o[0] = (bf16_t)v.x; o[1] = (bf16_t)v.y; o[2] = (bf16_t)v.z; o[3] = (bf16_t)v.w;
    *(bf16x4*)(projb + i) = o;
}

// ---------------- 128x64 BK=32 P=3 pipelined MFMA GEMM, hoisted addressing ----------------
template <int BM, int BN, int BK, int P, int ACT, int RES, int WF, int WB, int QKVE>
__global__ __launch_bounds__(256) void gemm_pipe(const bf16_t* __restrict__ A,
                                                 const bf16_t* __restrict__ Bt,
                                                 const float* __restrict__ bias,
                                                 float* __restrict__ Cf,
                                                 bf16_t* __restrict__ Cb,
                                                 bf16_t* __restrict__ Vt,
                                                 int N, int K) {
    static_assert(BK == 32, "BK fixed at 32 (KS==1)");
    constexpr int MR = BM / 2 / 16;
    constexpr int NR = BN / 2 / 16;
    constexpr int CH = BK / 8;
    constexpr int SWZ = CH - 1;
    constexpr int TILE = (BM + BN) * BK;
    constexpr int L = TILE / 8 / 256;
    __shared__ __attribute__((aligned(16))) bf16_t smem[P * TILE];
    int tid = threadIdx.x;
    int wv = tid >> 6, ln = tid & 63;
    int gx = gridDim.x;
    int lin = blockIdx.y * gx + blockIdx.x;
    int per = (gx * gridDim.y) >> 3;
    int orig = (lin & 7) * per + (lin >> 3);
    int m0 = (orig / gx) * BM, n0 = (orig % gx) * BN;
    int wr = (wv >> 1) * (MR * 16), wc = (wv & 1) * (NR * 16);
    int lr = ln & 15, kq8 = ln >> 4;
    int nsteps = K / BK;

    const bf16_t* gsrc[L];
    int ldst[L];
#pragma unroll
    for (int i = 0; i < L; i++) {
        int c = i * 256 + tid;
        int cb = i * 256 + (tid & ~63);
        bool inA = (c < BM * CH);
        int cc = inA ? c : c - BM * CH;
        int row = cc / CH, ch = cc % CH;
        const bf16_t* mat = inA ? A : Bt;
        int r0 = inA ? m0 : n0;
        int chs = ch ^ ((row ^ (row >> 2)) & SWZ);
        gsrc[i] = mat + (size_t)(r0 + row) * K + chs * 8;
        ldst[i] = cb * 8;
    }
    auto stage = [&](int tile, int sb) {
        int k0 = tile * BK;
        bf16_t* dst = smem + sb * TILE;
#pragma unroll
        for (int i = 0; i < L; i++)
            __builtin_amdgcn_global_load_lds(AS1(gsrc[i] + k0), AS3(dst + ldst[i]), 16, 0, 0);
    };

    int aoff[MR], boff[NR];
#pragma unroll
    for (int m = 0; m < MR; m++) {
        int row = wr + m * 16 + lr;
        aoff[m] = (row * CH + (kq8 ^ ((row ^ (row >> 2)) & SWZ))) * 8;
    }
#pragma unroll
    for (int n = 0; n < NR; n++) {
        int row = wc + n * 16 + lr;
        boff[n] = BM * BK + (row * CH + (kq8 ^ ((row ^ (row >> 2)) & SWZ))) * 8;
    }

    f32x4v acc[MR][NR] = {};
#pragma unroll
    for (int p = 0; p < P - 1; ++p) stage(p, p);

    int cur = 0;
    for (int t = 0; t < nsteps; ++t) {
        int rem = nsteps - 1 - t;
        if (rem >= P - 2) wait_vmcnt<(P - 2) * L>();
        else if constexpr (P >= 4) {
            if (rem == 1) wait_vmcnt<L>(); else wait_vmcnt<0>();
        } else wait_vmcnt<0>();
        __builtin_amdgcn_s_barrier();
        asm volatile("" ::: "memory");
        if (t + P - 1 < nsteps) {
            int sb = cur - 1; if (sb < 0) sb = P - 1;
            stage(t + P - 1, sb);
        }
        const bf16_t* base = smem + cur * TILE;
        bf16x8 af[MR], bfr[NR];
#pragma unroll
        for (int m = 0; m < MR; m++) af[m] = *(const bf16x8*)&base[aoff[m]];
#pragma unroll
        for (int n = 0; n < NR; n++) bfr[n] = *(const bf16x8*)&base[boff[n]];
        __builtin_amdgcn_s_setprio(1);
#pragma unroll
        for (int m = 0; m < MR; m++)
#pragma unroll
            for (int n = 0; n < NR; n++)
                acc[m][n] = __builtin_amdgcn_mfma_f32_16x16x32_bf16(af[m], bfr[n], acc[m][n], 0, 0, 0);
        __builtin_amdgcn_s_setprio(0);
        cur = (cur + 1 == P) ? 0 : cur + 1;
    }
    int rq = (ln >> 4) * 4;
    if (WB || QKVE) {
        __syncthreads();
        bf16_t* T = smem;
        constexpr int S = BN + 8;
#pragma unroll
        for (int n = 0; n < NR; n++) {
            int col = wc + n * 16 + lr;
            float bcol = bias[n0 + col];
#pragma unroll
            for (int m = 0; m < MR; m++) {
#pragma unroll
                for (int r = 0; r < 4; r++) {
                    int row = wr + m * 16 + rq + r;
                    float v = acc[m][n][r] + bcol;
                    if (ACT == 1) v = gelu_exact(v);
                    int cs = (col & 7) | ((((col >> 3) ^ (row >> 3)) & (BN / 8 - 1)) << 3);
                    T[row * S + cs] = (bf16_t)v;
                }
            }
        }
        __syncthreads();
        if (!QKVE || n0 < 1024) {
            int ldc = QKVE ? 1024 : N;
#pragma unroll
            for (int i = 0; i < BM * BN / 8 / 256; i++) {
                int e = i * 2048 + tid * 8;
                int row = e / BN, c0 = e % BN;
                int ch = ((c0 >> 3) ^ (row >> 3)) & (BN / 8 - 1);
                bf16x8 v = *(const bf16x8*)&T[row * S + ch * 8];
                *(bf16x8*)&Cb[(size_t)(m0 + row) * ldc + n0 + c0] = v;
            }
        } else {
#pragma unroll
            for (int i = 0; i < BM * BN / 8 / 256; i++) {
                int u = i * 256 + tid;
                int d = u & (BN - 1), nb8 = (u / BN) * 8;
                bf16x8 v;
#pragma unroll
                for (int j = 0; j < 8; j++) {
                    int row = nb8 + j;
                    int cs = (d & 7) | ((((d >> 3) ^ (row >> 3)) & (BN / 8 - 1)) << 3);
                    v[j] = T[row * S + cs];
                }
                int gcol = n0 + d;
                int hh2 = (gcol >> 6) & 7, dd2 = gcol & 63;
                int grow = m0 + nb8;
                int bb = grow >> 12, nn = grow & 4095;
                *(bf16x8*)&Vt[(((size_t)bb * 8 + hh2) * 64 + dd2) * 4096 + nn] = v;
            }
        }
    } else {
#pragma unroll
        for (int n = 0; n < NR; n++) {
            int col = n0 + wc + n * 16 + lr;
            float bcol = bias[col];
#pragma unroll
            for (int m = 0; m < MR; m++) {
#pragma unroll
                for (int r = 0; r < 4; r++) {
                    int row = m0 + wr + m * 16 + rq + r;
                    float v = acc[m][n][r] + bcol;
                    if (ACT == 1) v = gelu_exact(v);
                    size_t idx = (size_t)row * N + col;
                    if (RES) Cf[idx] += v;
                    else Cf[idx] = v;
                }
            }
        }
    }
}

// ---------------- K-feature GEMM (single pass, shift-invariant kmx=0) ----------------
// kp = RATIO*(exp(dd*DN - diag) + EPS). Uniform per-(b,h) shift cancels in the
// attention output except through EPS (perturbation ~1e-3, far below threshold).
__global__ __launch_bounds__(256) void feat_kernel(const bf16_t* __restrict__ qkvb,
                                                   const bf16_t* __restrict__ projb,
                                                   bf16_t* __restrict__ outp,
                                                   float* __restrict__ ksum_part) {
    int bid = blockIdx.x;
    int bh = bid >> 5, tile = bid & 31;
    int b = bh >> 3, hh = bh & 7;
    int tid = threadIdx.x, wv = tid >> 6, ln = tid & 63;
    __shared__ __attribute__((aligned(16))) bf16_t As[128 * 64];
    __shared__ __attribute__((aligned(16))) bf16_t Bs[256 * 64];
    __shared__ float diag_s[128];
    __shared__ float ksp_s[256];
    int n0 = tile * 128;
    int qoff = 512 + hh * 64;
    int lrow8 = ln >> 3;
    int lchunk = ((ln & 7) ^ (lrow8 & 7)) * 8;
#pragma unroll
    for (int i = 0; i < 4; i++) {
        int e = wv * 4 + i;
        size_t src = (size_t)(b * SEQN + n0 + e * 8 + lrow8) * 1024 + qoff + lchunk;
        __builtin_amdgcn_global_load_lds(AS1(qkvb + src), AS3(&As[e * 512]), 16, 0, 0);
    }
#pragma unroll
    for (int i = 0; i < 8; i++) {
        int e = wv * 8 + i;
        size_t src = (size_t)(e * 8 + lrow8) * 64 + lchunk;
        __builtin_amdgcn_global_load_lds(AS1(projb + src), AS3(&Bs[e * 512]), 16, 0, 0);
    }
    __syncthreads();
    if (tid < 128) {
        float s = 0.f;
#pragma unroll
        for (int c = 0; c < 8; c++) {
            bf16x8 v = *(const bf16x8*)&As[tid * 64 + ((c ^ (tid & 7)) * 8)];
#pragma unroll
            for (int j = 0; j < 8; j++) { float f = (float)v[j]; s += f * f; }
        }
        diag_s[tid] = s * (0.5f * DN * DN);
    }
    int wr = (wv >> 1) * 64, wc = (wv & 1) * 128;
    int lr = ln & 15, kg = ln >> 4, rq = kg * 4;
    f32x4v acc[4][8] = {};
#pragma unroll
    for (int ks = 0; ks < 2; ks++) {
        int g = ks * 4 + kg;
        bf16x8 af[4], bfv[8];
#pragma unroll
        for (int m = 0; m < 4; m++) {
            int row = wr + m * 16 + lr;
            af[m] = *(const bf16x8*)&As[row * 64 + ((g ^ (row & 7)) * 8)];
        }
#pragma unroll
        for (int n = 0; n < 8; n++) {
            int row = wc + n * 16 + lr;
            bfv[n] = *(const bf16x8*)&Bs[row * 64 + ((g ^ (row & 7)) * 8)];
        }
#pragma unroll
        for (int m = 0; m < 4; m++)
#pragma unroll
            for (int n = 0; n < 8; n++)
                acc[m][n] = __builtin_amdgcn_mfma_f32_16x16x32_bf16(af[m], bfv[n], acc[m][n], 0, 0, 0);
    }
    __syncthreads();   // diag_s visible to all
    float sj[8] = {};
#pragma unroll
    for (int m = 0; m < 4; m++) {
#pragma unroll
        for (int n = 0; n < 8; n++) {
            int col = wc + n * 16 + lr;
            bf16x4 pk;
#pragma unroll
            for (int r = 0; r < 4; r++) {
                int row = wr + m * 16 + rq + r;
                float val = RATIO * (expf(acc[m][n][r] * DN - diag_s[row]) + EPSK);
                pk[r] = (bf16_t)val;
                sj[n] += val;
            }
            *(bf16x4*)&outp[((size_t)bh * MF + col) * 4096 + n0 + wr + m * 16 + rq] = pk;
        }
    }
#pragma unroll
    for (int n = 0; n < 8; n++) {
        sj[n] += __shfl_xor(sj[n], 16);
        sj[n] += __shfl_xor(sj[n], 32);
    }
    if (wv < 2 && ln < 16) {
#pragma unroll
        for (int n = 0; n < 8; n++) ksp_s[wc + n * 16 + ln] = sj[n];
    }
    __syncthreads();
    if (wv >= 2 && ln < 16) {
#pragma unroll
        for (int n = 0; n < 8; n++) ksp_s[wc + n * 16 + ln] += sj[n];
    }
    __syncthreads();
    ksum_part[(size_t)bid * 256 + tid] = ksp_s[tid];
}

// ---------------- ctx split-K GEMM ----------------
__global__ __launch_bounds__(256) void ctx_gemm(const bf16_t* __restrict__ KPt,
                                                const bf16_t* __restrict__ Vt,
                                                float* __restrict__ part) {
    int bh = blockIdx.y;
    int mtile = blockIdx.x & 1, kc = blockIdx.x >> 1;
    int m0 = mtile * 128, nb = kc * 512;
    int tid = threadIdx.x, wv = tid >> 6, ln = tid & 63;
    __shared__ __attribute__((aligned(16))) bf16_t As[128 * 64];
    __shared__ __attribute__((aligned(16))) bf16_t Bs[64 * 64];
    int lrow8 = ln >> 3;
    int lchunk = ((ln & 7) ^ (lrow8 & 7)) * 8;
    int lr = ln & 15, kg = ln >> 4, rq = kg * 4;
    int wr = wv * 32;
    f32x4v acc[2][4] = {};
    for (int kt = 0; kt < 8; kt++) {
        int noff = nb + kt * 64;
        __syncthreads();
#pragma unroll
        for (int i = 0; i < 4; i++) {
            int e = wv * 4 + i;
            __builtin_amdgcn_global_load_lds(
                AS1(KPt + ((size_t)bh * MF + m0 + e * 8 + lrow8) * 4096 + noff + lchunk),
                AS3(&As[e * 512]), 16, 0, 0);
        }
#pragma unroll
        for (int i = 0; i < 2; i++) {
            int e = wv * 2 + i;
            __builtin_amdgcn_global_load_lds(
                AS1(Vt + ((size_t)bh * 64 + e * 8 + lrow8) * 4096 + noff + lchunk),
                AS3(&Bs[e * 512]), 16, 0, 0);
        }
        __syncthreads();
#pragma unroll
        for (int ks = 0; ks < 2; ks++) {
            int g = ks * 4 + kg;
            bf16x8 af[2], bfv[4];
#pragma unroll
            for (int m = 0; m < 2; m++) {
                int row = wr + m * 16 + lr;
                af[m] = *(const bf16x8*)&As[row * 64 + ((g ^ (row & 7)) * 8)];
            }
#pragma unroll
            for (int n = 0; n < 4; n++) {
                int row = n * 16 + lr;
                bfv[n] = *(const bf16x8*)&Bs[row * 64 + ((g ^ (row & 7)) * 8)];
            }
#pragma unroll
            for (int m = 0; m < 2; m++)
#pragma unroll
                for (int n = 0; n < 4; n++)
                    acc[m][n] = __builtin_amdgcn_mfma_f32_16x16x32_bf16(af[m], bfv[n], acc[m][n], 0, 0, 0);
        }
    }
#pragma unroll
    for (int m = 0; m < 2; m++)
#pragma unroll
        for (int n = 0; n < 4; n++)
#pragma unroll
            for (int r = 0; r < 4; r++)
                part[((size_t)(kc * 16 + bh) * MF + m0 + wr + m * 16 + rq + r) * 64 + n * 16 + lr] =
                    acc[m][n][r];
}

// ---------------- ctx reduce -> ctx_t[bh][d][m] bf16; + ksum reduce ----------------
__global__ __launch_bounds__(256) void ctx_reduce_kernel(const float* __restrict__ part,
                                                         const float* __restrict__ ksum_part,
                                                         bf16_t* __restrict__ ctx_t,
                                                         float* __restrict__ ksum) {
    int bh = blockIdx.x;
    for (int it = 0; it < 64; it++) {
        int idx = it * 256 + threadIdx.x;
        int m = idx >> 6, d = idx & 63;
        float s = 0.f;
#pragma unroll
        for (int kc = 0; kc < 8; kc++)
            s += part[(size_t)(kc * 16 + bh) * 16384 + idx];
        ctx_t[((size_t)bh * 64 + d) * MF + m] = (bf16_t)s;
    }
    {
        float s = 0.f;
#pragma unroll
        for (int t = 0; t < 32; t++)
            s += ksum_part[((size_t)bh * 32 + t) * 256 + threadIdx.x];
        ksum[bh * MF + threadIdx.x] = s;
    }
}

// ---------------- fused Q-side: q-features + dinv + (qp@ctx)*dinv -> abuf ----------------
// qp = RATIO*(exp(dd*DN - diag) + EPS); per-row shift cancels in out except via EPS.
__global__ __launch_bounds__(256) void qfused_kernel(const bf16_t* __restrict__ qkvb,
                                                     const bf16_t* __restrict__ projb,
                                                     const bf16_t* __restrict__ ctx_t,
                                                     const float* __restrict__ ksumb,
                                                     bf16_t* __restrict__ abuf) {
    int bid = blockIdx.x;
    int bh = bid >> 5, tile = bid & 31;
    int b = bh >> 3, hh = bh & 7;
    int tid = threadIdx.x, wv = tid >> 6, ln = tid & 63;
    __shared__ __attribute__((aligned(16))) bf16_t Qs[128 * 64];
    __shared__ __attribute__((aligned(16))) bf16_t Ps[256 * 64];
    __shared__ __attribute__((aligned(16))) bf16_t Cs[64 * 256];
    __shared__ float diag_s[128];
    __shared__ float dsum_s[128];
    int n0 = tile * 128;
    int lrow8 = ln >> 3;
    int lchunk = ((ln & 7) ^ (lrow8 & 7)) * 8;
#pragma unroll
    for (int i = 0; i < 4; i++) {
        int e = wv * 4 + i;
        size_t src = (size_t)(b * SEQN + n0 + e * 8 + lrow8) * 1024 + hh * 64 + lchunk;
        __builtin_amdgcn_global_load_lds(AS1(qkvb + src), AS3(&Qs[e * 512]), 16, 0, 0);
    }
#pragma unroll
    for (int i = 0; i < 8; i++) {
        int e = wv * 8 + i;
        size_t src = (size_t)(e * 8 + lrow8) * 64 + lchunk;
        __builtin_amdgcn_global_load_lds(AS1(projb + src), AS3(&Ps[e * 512]), 16, 0, 0);
    }
#pragma unroll
    for (int i = 0; i < 8; i++) {
        int c = i * 256 + tid;
        int cb = i * 256 + (tid & ~63);
        int crow = c >> 5, cch = c & 31;
        size_t src = ((size_t)bh * 64 + crow) * 256 + (size_t)(cch ^ (crow & 7)) * 8;
        __builtin_amdgcn_global_load_lds(AS1(ctx_t + src), AS3(Cs + (size_t)cb * 8), 16, 0, 0);
    }
    int wr = (wv >> 1) * 64, wc = (wv & 1) * 128;
    int lr = ln & 15, kg = ln >> 4, rq = kg * 4;
    float ksum_r[8];
#pragma unroll
    for (int n = 0; n < 8; n++) ksum_r[n] = ksumb[bh * MF + wc + n * 16 + lr];
    __syncthreads();
    if (tid < 128) {
        float s = 0.f;
#pragma unroll
        for (int c = 0; c < 8; c++) {
            bf16x8 v = *(const bf16x8*)&Qs[tid * 64 + ((c ^ (tid & 7)) * 8)];
#pragma unroll
            for (int j = 0; j < 8; j++) { float f = (float)v[j]; s += f * f; }
        }
        diag_s[tid] = s * (0.5f * DN * DN);
    }
    f32x4v acc[4][8] = {};
#pragma unroll
    for (int ks = 0; ks < 2; ks++) {
        int g = ks * 4 + kg;
        bf16x8 af[4], bfv[8];
#pragma unroll
        for (int m = 0; m < 4; m++) {
            int row = wr + m * 16 + lr;
            af[m] = *(const bf16x8*)&Qs[row * 64 + ((g ^ (row & 7)) * 8)];
        }
#pragma unroll
        for (int n = 0; n < 8; n++) {
            int row = wc + n * 16 + lr;
            bfv[n] = *(const bf16x8*)&Ps[row * 64 + ((g ^ (row & 7)) * 8)];
        }
#pragma unroll
        for (int m = 0; m < 4; m++)
#pragma unroll
            for (int n = 0; n < 8; n++)
                acc[m][n] = __builtin_amdgcn_mfma_f32_16x16x32_bf16(af[m], bfv[n], acc[m][n], 0, 0, 0);
    }
    __syncthreads();   // diag_s visible
    float dsum_p[4][4];
#pragma unroll
    for (int m = 0; m < 4; m++) {
#pragma unroll
        for (int r = 0; r < 4; r++) {
            int row = wr + m * 16 + rq + r;
            float dg = diag_s[row];
            float ds = 0.f;
#pragma unroll
            for (int n = 0; n < 8; n++) {
                float val = RATIO * (expf(acc[m][n][r] * DN - dg) + EPSK);
                acc[m][n][r] = val;
                ds += val * ksum_r[n];
            }
            dsum_p[m][r] = ds;
        }
    }
#pragma unroll
    for (int m = 0; m < 4; m++)
#pragma unroll
        for (int r = 0; r < 4; r++) {
#pragma unroll
            for (int mask = 1; mask < 16; mask <<= 1)
                dsum_p[m][r] += __shfl_xor(dsum_p[m][r], mask);
        }
    if ((wv & 1) == 0 && lr == 0) {
#pragma unroll
        for (int m = 0; m < 4; m++)
#pragma unroll
            for (int r = 0; r < 4; r++)
                dsum_s[wr + m * 16 + rq + r] = dsum_p[m][r];
    }
    __syncthreads();
    if ((wv & 1) == 1 && lr == 0) {
#pragma unroll
        for (int m = 0; m < 4; m++)
#pragma unroll
            for (int r = 0; r < 4; r++) {
                int row = wr + m * 16 + rq + r;
                dsum_s[row] = 1.0f / (dsum_s[row] + dsum_p[m][r]);
            }
    }
    __syncthreads();
    f32x4v acc_o[4][2] = {};
#pragma unroll
    for (int h = 0; h < 2; h++) {
        if ((wv & 1) == h) {
#pragma unroll
            for (int m = 0; m < 4; m++)
#pragma unroll
                for (int n = 0; n < 8; n++)
#pragma unroll
                    for (int r = 0; r < 4; r++) {
                        int row = wr + m * 16 + rq + r;
                        int ml = n * 16 + lr;
                        Ps[row * 128 + (((ml >> 3) ^ (row & 7)) * 8) + (ml & 7)] =
                            (bf16_t)acc[m][n][r];
                    }
        }
        __syncthreads();
#pragma unroll
        for (int ku = 0; ku < 4; ku++) {
            int g = ku * 4 + kg;
            bf16x8 af[4], bfv[2];
#pragma unroll
            for (int m = 0; m < 4; m++) {
                int row = wr + m * 16 + lr;
                af[m] = *(const bf16x8*)&Ps[row * 128 + ((g ^ (row & 7)) * 8)];
            }
#pragma unroll
            for (int n = 0; n < 2; n++) {
                int rowd = (wv & 1) * 32 + n * 16 + lr;
                int ch = (h * 16 + g) ^ (rowd & 7);
                bfv[n] = *(const bf16x8*)&Cs[(rowd * 32 + ch) * 8];
            }
#pragma unroll
            for (int m = 0; m < 4; m++)
#pragma unroll
                for (int n = 0; n < 2; n++)
                    acc_o[m][n] = __builtin_amdgcn_mfma_f32_16x16x32_bf16(af[m], bfv[n], acc_o[m][n], 0, 0, 0);
        }
        __syncthreads();
    }
#pragma unroll
    for (int m = 0; m < 4; m++) {
#pragma unroll
        for (int r = 0; r < 4; r++) {
            int rowl = wr + m * 16 + rq + r;
            float di = dsum_s[rowl];
            size_t obase = ((size_t)(b * SEQN + n0 + rowl)) * DMODEL + hh * 64;
#pragma unroll
            for (int n = 0; n < 2; n++) {
                int d = (wv & 1) * 32 + n * 16 + lr;
                abuf[obase + d] = (bf16_t)(acc_o[m][n][r] * di);
            }
        }
    }
}

extern "C" void kernel_launch(void* const* d_in, const int* in_sizes, int n_in,
                              void* d_out, int out_size, void* d_ws, size_t ws_size,
                              hipStream_t stream) {
    const float* x     = (const float*)d_in[0];
    const float* proj  = (const float*)d_in[1];
    const float* ln1_g = (const float*)d_in[2];
    const float* ln1_b = (const float*)d_in[3];
    const float* Wqkv  = (const float*)d_in[4];
    const float* bqkv  = (const float*)d_in[5];
    const float* Wo    = (const float*)d_in[6];
    const float* bo    = (const float*)d_in[7];
    const float* ln2_g = (const float*)d_in[8];
    const float* ln2_b = (const float*)d_in[9];
    const float* Wff1  = (const float*)d_in[10];
    const float* bff1  = (const float*)d_in[11];
    const float* Wff2  = (const float*)d_in[12];
    const float* bff2  = (const float*)d_in[13];

    float* h = (float*)d_out;
    char* ws = (char*)d_ws;
    bf16_t* KPt   = (bf16_t*)(ws);
    bf16_t* ybf   = (bf16_t*)(ws);               // [0, 8Mi)   (dead when KPt live)
    bf16_t* pWo   = (bf16_t*)(ws + 8388608);     // [8Mi,16Mi)
    bf16_t* pFF2  = (bf16_t*)(ws + 16777216);    // [16Mi,24Mi)
    bf16_t* qkvb  = (bf16_t*)(ws + 33554432);
    bf16_t* abufb = (bf16_t*)(ws + 50331648);
    float*  ctx_part  = (float*)(ws + 58720256);
    float*  ksum_part = (float*)(ws + 67108864);
    bf16_t* ffmidb    = (bf16_t*)(ws + 50331648);
    bf16_t* Vt    = (bf16_t*)(ws + 83886080);
    bf16_t* projb = (bf16_t*)(ws + 92274688);
    bf16_t* ctx_t = (bf16_t*)(ws + 92405760);
    float*  ksumb = (float*)(ws + 92930048);
    bf16_t* wbase = (bf16_t*)(ws + 93061120);
    const size_t WSLOT = 3407872;
    bool hoist = ws_size >= (size_t)93061120 + 4 * 6815744;

    hipMemcpyAsync(h, x, (size_t)NROWS * DMODEL * sizeof(float),
                   hipMemcpyDeviceToDevice, stream);
    pconv_kernel<<<64, 256, 0, stream>>>(proj, projb);
    if (hoist)
        wconv_all<<<dim3(3072, 4), 256, 0, stream>>>(Wqkv, Wo, Wff1, Wff2, wbase);

    for (int i = 0; i < DEPTH; i++) {
        const bf16_t* pj = projb + (size_t)i * MF * DH;
        if (!hoist)
            wconv_all<<<dim3(3072, 1), 256, 0, stream>>>(
                Wqkv + (size_t)i * 786432, Wo + (size_t)i * 262144,
                Wff1 + (size_t)i * 1048576, Wff2 + (size_t)i * 1048576, wbase);
        bf16_t* wl = wbase + (hoist ? (size_t)i * WSLOT : 0);
        bf16_t* wq_t = wl;
        bf16_t* wo_t = wl + 786432;
        bf16_t* w1_t = wl + 1048576;
        bf16_t* w2_t = wl + 2097152;

        if (i == 0)
            ln_kernel<<<NROWS, 256, 0, stream>>>(h, ln1_g, ln1_b, ybf);
        else
            ln_add_kernel<<<NROWS, 256, 0, stream>>>(h, pFF2, ln1_g + i * DMODEL,
                                                     ln1_b + i * DMODEL, ybf);
        gemm_pipe<128, 64, 32, 3, 0, 0, 0, 0, 1>
            <<<dim3(1536 / 64, NROWS / 128), 256, 0, stream>>>(
            ybf, wq_t, bqkv + i * 1536, nullptr, qkvb, Vt, 1536, 512);
        feat_kernel<<<512, 256, 0, stream>>>(qkvb, pj, KPt, ksum_part);
        ctx_gemm<<<dim3(16, 16), 256, 0, stream>>>(KPt, Vt, ctx_part);
        ctx_reduce_kernel<<<16, 256, 0, stream>>>(ctx_part, ksum_part, ctx_t, ksumb);
        qfused_kernel<<<512, 256, 0, stream>>>(qkvb, pj, ctx_t, ksumb, abufb);
        gemm_pipe<128, 64, 32, 3, 0, 0, 0, 1, 0>
            <<<dim3(512 / 64, NROWS / 128), 256, 0, stream>>>(
            abufb, wo_t, bo + i * DMODEL, nullptr, pWo, nullptr, 512, 512);

        ln_add_kernel<<<NROWS, 256, 0, stream>>>(h, pWo, ln2_g + i * DMODEL,
                                                 ln2_b + i * DMODEL, ybf);
        gemm_pipe<128, 64, 32, 3, 1, 0, 0, 1, 0>
            <<<dim3(2048 / 64, NROWS / 128), 256, 0, stream>>>(
            ybf, w1_t, bff1 + i * FFD, nullptr, ffmidb, nullptr, 2048, 512);
        gemm_pipe<128, 64, 32, 3, 0, 0, 0, 1, 0>
            <<<dim3(512 / 64, NROWS / 128), 256, 0, stream>>>(
            ffmidb, w2_t, bff2 + i * DMODEL, nullptr, pFF2, nullptr, 512, 2048);
    }
    add_kernel<<<4096, 256, 0, stream>>>(h, pFF2);
}

// Round 17
// 789.590 us; speedup vs baseline: 1.1391x; 1.0633x over previous
//
#include <hip/hip_runtime.h>
#include <math.h>

#define DEPTH 4
#define DMODEL 512
#define DH 64
#define MF 256
#define FFD 2048
#define SEQN 4096
#define NROWS 8192

typedef __bf16 bf16_t;
typedef bf16_t bf16x8 __attribute__((ext_vector_type(8)));
typedef bf16_t bf16x4 __attribute__((ext_vector_type(4)));
typedef bf16_t bf16x2 __attribute__((ext_vector_type(2)));
typedef float f32x4v __attribute__((ext_vector_type(4)));

static constexpr float DN = 0.35355339059327373f;   // 64^-0.25
static constexpr float RATIO = 0.0625f;             // 256^-0.5
static constexpr float EPSK = 1e-4f;

// tanh-approx GELU in sigmoid form: x * sigmoid(2*0.79788456*(x + 0.044715 x^3))
__device__ __forceinline__ float gelu_fast(float x) {
    float z2 = x * (1.5957691216f + 0.0713548162f * x * x);   // 2*z
    return x / (1.0f + __expf(-z2));
}

#define AS1(p) ((const __attribute__((address_space(1))) void*)(p))
#define AS3(p) ((__attribute__((address_space(3))) void*)(p))

template <int N> __device__ __forceinline__ void wait_vmcnt() {
    if constexpr (N == 0) asm volatile("s_waitcnt vmcnt(0)" ::: "memory");
    else if constexpr (N == 1) asm volatile("s_waitcnt vmcnt(1)" ::: "memory");
    else if constexpr (N == 2) asm volatile("s_waitcnt vmcnt(2)" ::: "memory");
    else if constexpr (N == 3) asm volatile("s_waitcnt vmcnt(3)" ::: "memory");
    else if constexpr (N == 4) asm volatile("s_waitcnt vmcnt(4)" ::: "memory");
    else if constexpr (N == 5) asm volatile("s_waitcnt vmcnt(5)" ::: "memory");
    else if constexpr (N == 6) asm volatile("s_waitcnt vmcnt(6)" ::: "memory");
    else if constexpr (N == 8) asm volatile("s_waitcnt vmcnt(8)" ::: "memory");
    else asm volatile("s_waitcnt vmcnt(12)" ::: "memory");
}

// ---------------- LayerNorm -> bf16 (no residual) ----------------
__global__ __launch_bounds__(256) void ln_kernel(const float* __restrict__ h,
                                                 const float* __restrict__ g,
                                                 const float* __restrict__ b,
                                                 bf16_t* __restrict__ y) {
    int row = blockIdx.x, tid = threadIdx.x;
    const float* hr = h + (size_t)row * DMODEL;
    float v0 = hr[tid], v1 = hr[tid + 256];
    __shared__ float s_sum[256], s_sq[256];
    s_sum[tid] = v0 + v1;
    s_sq[tid] = v0 * v0 + v1 * v1;
    __syncthreads();
    for (int off = 128; off > 0; off >>= 1) {
        if (tid < off) { s_sum[tid] += s_sum[tid + off]; s_sq[tid] += s_sq[tid + off]; }
        __syncthreads();
    }
    float mu = s_sum[0] * (1.0f / DMODEL);
    float var = s_sq[0] * (1.0f / DMODEL) - mu * mu;
    float rstd = rsqrtf(var + 1e-5f);
    bf16_t* yr = y + (size_t)row * DMODEL;
    yr[tid]       = (bf16_t)((v0 - mu) * rstd * g[tid] + b[tid]);
    yr[tid + 256] = (bf16_t)((v1 - mu) * rstd * g[tid + 256] + b[tid + 256]);
}

// ---------------- fused: h += P (bf16); LayerNorm(h) -> bf16; h written back ----------------
__global__ __launch_bounds__(256) void ln_add_kernel(float* __restrict__ h,
                                                     const bf16_t* __restrict__ p,
                                                     const float* __restrict__ g,
                                                     const float* __restrict__ b,
                                                     bf16_t* __restrict__ y) {
    int row = blockIdx.x, tid = threadIdx.x;
    float* hr = h + (size_t)row * DMODEL;
    const bf16_t* pr = p + (size_t)row * DMODEL;
    float2 hv = *(const float2*)(hr + 2 * tid);
    bf16x2 pv = *(const bf16x2*)(pr + 2 * tid);
    float v0 = hv.x + (float)pv[0];
    float v1 = hv.y + (float)pv[1];
    float2 outv; outv.x = v0; outv.y = v1;
    *(float2*)(hr + 2 * tid) = outv;
    __shared__ float s_sum[256], s_sq[256];
    s_sum[tid] = v0 + v1;
    s_sq[tid] = v0 * v0 + v1 * v1;
    __syncthreads();
    for (int off = 128; off > 0; off >>= 1) {
        if (tid < off) { s_sum[tid] += s_sum[tid + off]; s_sq[tid] += s_sq[tid + off]; }
        __syncthreads();
    }
    float mu = s_sum[0] * (1.0f / DMODEL);
    float var = s_sq[0] * (1.0f / DMODEL) - mu * mu;
    float rstd = rsqrtf(var + 1e-5f);
    bf16x2 ov;
    ov[0] = (bf16_t)((v0 - mu) * rstd * g[2 * tid] + b[2 * tid]);
    ov[1] = (bf16_t)((v1 - mu) * rstd * g[2 * tid + 1] + b[2 * tid + 1]);
    *(bf16x2*)(y + (size_t)row * DMODEL + 2 * tid) = ov;
}

// ---------------- tail: h += P (bf16) ----------------
__global__ __launch_bounds__(256) void add_kernel(float* __restrict__ h,
                                                  const bf16_t* __restrict__ p) {
    size_t i = ((size_t)blockIdx.x * 256 + threadIdx.x) * 4;
    float4 hv = *(const float4*)(h + i);
    bf16x4 pv = *(const bf16x4*)(p + i);
    hv.x += (float)pv[0]; hv.y += (float)pv[1];
    hv.z += (float)pv[2]; hv.w += (float)pv[3];
    *(float4*)(h + i) = hv;
}

// ---------------- weight transpose+convert; blockIdx.y = layer offset ----------------
__global__ __launch_bounds__(256) void wconv_all(const float* __restrict__ Wqkv,
                                                 const float* __restrict__ Wo,
                                                 const float* __restrict__ Wff1,
                                                 const float* __restrict__ Wff2,
                                                 bf16_t* __restrict__ wslot) {
    __shared__ float t[32][33];
    int layer = blockIdx.y;
    int bid = blockIdx.x;
    const float* W; bf16_t* Wt; int K, N, nx, lb;
    bf16_t* slot = wslot + (size_t)layer * 3407872;
    if (bid < 768)       { W = Wqkv + (size_t)layer * 786432;  Wt = slot;           K = 512;  N = 1536; nx = 48; lb = bid; }
    else if (bid < 1024) { W = Wo   + (size_t)layer * 262144;  Wt = slot + 786432;  K = 512;  N = 512;  nx = 16; lb = bid - 768; }
    else if (bid < 2048) { W = Wff1 + (size_t)layer * 1048576; Wt = slot + 1048576; K = 512;  N = 2048; nx = 64; lb = bid - 1024; }
    else                 { W = Wff2 + (size_t)layer * 1048576; Wt = slot + 2097152; K = 2048; N = 512;  nx = 16; lb = bid - 2048; }
    int n0 = (lb % nx) * 32, k0 = (lb / nx) * 32;
    int tx = threadIdx.x & 31, ty = threadIdx.x >> 5;
#pragma unroll
    for (int i = 0; i < 32; i += 8)
        t[ty + i][tx] = W[(size_t)(k0 + ty + i) * N + n0 + tx];
    __syncthreads();
#pragma unroll
    for (int i = 0; i < 32; i += 8)
        Wt[(size_t)(n0 + ty + i) * K + k0 + tx] = (bf16_t)t[tx][ty + i];
}

// ---------------- proj -> bf16 ----------------
__global__ __launch_bounds__(256) void pconv_kernel(const float* __restrict__ proj,
                                                    bf16_t* __restrict__ projb) {
    int i = (blockIdx.x * 256 + threadIdx.x) * 4;
    float4 v = *(const float4*)(proj + i);
    bf16x4 o;
    o[0] = (bf16_t)v.x; o[1] = (bf16_t)v.y; o[2] = (bf16_t)v.z; o[3] = (bf16_t)v.w;
    *(bf16x4*)(projb + i) = o;
}

// ---------------- 128x64 BK=32 P=3 pipelined MFMA GEMM, hoisted addressing ----------------
template <int BM, int BN, int BK, int P, int ACT, int RES, int WF, int WB, int QKVE>
__global__ __launch_bounds__(256) void gemm_pipe(const bf16_t* __restrict__ A,
                                                 const bf16_t* __restrict__ Bt,
                                                 const float* __restrict__ bias,
                                                 float* __restrict__ Cf,
                                                 bf16_t* __restrict__ Cb,
                                                 bf16_t* __restrict__ Vt,
                                                 int N, int K) {
    static_assert(BK == 32, "BK fixed at 32 (KS==1)");
    constexpr int MR = BM / 2 / 16;
    constexpr int NR = BN / 2 / 16;
    constexpr int CH = BK / 8;
    constexpr int SWZ = CH - 1;
    constexpr int TILE = (BM + BN) * BK;
    constexpr int L = TILE / 8 / 256;
    __shared__ __attribute__((aligned(16))) bf16_t smem[P * TILE];
    int tid = threadIdx.x;
    int wv = tid >> 6, ln = tid & 63;
    int gx = gridDim.x;
    int lin = blockIdx.y * gx + blockIdx.x;
    int per = (gx * gridDim.y) >> 3;
    int orig = (lin & 7) * per + (lin >> 3);
    int m0 = (orig / gx) * BM, n0 = (orig % gx) * BN;
    int wr = (wv >> 1) * (MR * 16), wc = (wv & 1) * (NR * 16);
    int lr = ln & 15, kq8 = ln >> 4;
    int nsteps = K / BK;

    const bf16_t* gsrc[L];
    int ldst[L];
#pragma unroll
    for (int i = 0; i < L; i++) {
        int c = i * 256 + tid;
        int cb = i * 256 + (tid & ~63);
        bool inA = (c < BM * CH);
        int cc = inA ? c : c - BM * CH;
        int row = cc / CH, ch = cc % CH;
        const bf16_t* mat = inA ? A : Bt;
        int r0 = inA ? m0 : n0;
        int chs = ch ^ ((row ^ (row >> 2)) & SWZ);
        gsrc[i] = mat + (size_t)(r0 + row) * K + chs * 8;
        ldst[i] = cb * 8;
    }
    auto stage = [&](int tile, int sb) {
        int k0 = tile * BK;
        bf16_t* dst = smem + sb * TILE;
#pragma unroll
        for (int i = 0; i < L; i++)
            __builtin_amdgcn_global_load_lds(AS1(gsrc[i] + k0), AS3(dst + ldst[i]), 16, 0, 0);
    };

    int aoff[MR], boff[NR];
#pragma unroll
    for (int m = 0; m < MR; m++) {
        int row = wr + m * 16 + lr;
        aoff[m] = (row * CH + (kq8 ^ ((row ^ (row >> 2)) & SWZ))) * 8;
    }
#pragma unroll
    for (int n = 0; n < NR; n++) {
        int row = wc + n * 16 + lr;
        boff[n] = BM * BK + (row * CH + (kq8 ^ ((row ^ (row >> 2)) & SWZ))) * 8;
    }

    f32x4v acc[MR][NR] = {};
#pragma unroll
    for (int p = 0; p < P - 1; ++p) stage(p, p);

    int cur = 0;
    for (int t = 0; t < nsteps; ++t) {
        int rem = nsteps - 1 - t;
        if (rem >= P - 2) wait_vmcnt<(P - 2) * L>();
        else if constexpr (P >= 4) {
            if (rem == 1) wait_vmcnt<L>(); else wait_vmcnt<0>();
        } else wait_vmcnt<0>();
        __builtin_amdgcn_s_barrier();
        asm volatile("" ::: "memory");
        if (t + P - 1 < nsteps) {
            int sb = cur - 1; if (sb < 0) sb = P - 1;
            stage(t + P - 1, sb);
        }
        const bf16_t* base = smem + cur * TILE;
        bf16x8 af[MR], bfr[NR];
#pragma unroll
        for (int m = 0; m < MR; m++) af[m] = *(const bf16x8*)&base[aoff[m]];
#pragma unroll
        for (int n = 0; n < NR; n++) bfr[n] = *(const bf16x8*)&base[boff[n]];
        __builtin_amdgcn_s_setprio(1);
#pragma unroll
        for (int m = 0; m < MR; m++)
#pragma unroll
            for (int n = 0; n < NR; n++)
                acc[m][n] = __builtin_amdgcn_mfma_f32_16x16x32_bf16(af[m], bfr[n], acc[m][n], 0, 0, 0);
        __builtin_amdgcn_s_setprio(0);
        cur = (cur + 1 == P) ? 0 : cur + 1;
    }
    int rq = (ln >> 4) * 4;
    if (WB || QKVE) {
        __syncthreads();
        bf16_t* T = smem;
        constexpr int S = BN + 8;
#pragma unroll
        for (int n = 0; n < NR; n++) {
            int col = wc + n * 16 + lr;
            float bcol = bias[n0 + col];
#pragma unroll
            for (int m = 0; m < MR; m++) {
#pragma unroll
                for (int r = 0; r < 4; r++) {
                    int row = wr + m * 16 + rq + r;
                    float v = acc[m][n][r] + bcol;
                    if (ACT == 1) v = gelu_fast(v);
                    int cs = (col & 7) | ((((col >> 3) ^ (row >> 3)) & (BN / 8 - 1)) << 3);
                    T[row * S + cs] = (bf16_t)v;
                }
            }
        }
        __syncthreads();
        if (!QKVE || n0 < 1024) {
            int ldc = QKVE ? 1024 : N;
#pragma unroll
            for (int i = 0; i < BM * BN / 8 / 256; i++) {
                int e = i * 2048 + tid * 8;
                int row = e / BN, c0 = e % BN;
                int ch = ((c0 >> 3) ^ (row >> 3)) & (BN / 8 - 1);
                bf16x8 v = *(const bf16x8*)&T[row * S + ch * 8];
                *(bf16x8*)&Cb[(size_t)(m0 + row) * ldc + n0 + c0] = v;
            }
        } else {
#pragma unroll
            for (int i = 0; i < BM * BN / 8 / 256; i++) {
                int u = i * 256 + tid;
                int d = u & (BN - 1), nb8 = (u / BN) * 8;
                bf16x8 v;
#pragma unroll
                for (int j = 0; j < 8; j++) {
                    int row = nb8 + j;
                    int cs = (d & 7) | ((((d >> 3) ^ (row >> 3)) & (BN / 8 - 1)) << 3);
                    v[j] = T[row * S + cs];
                }
                int gcol = n0 + d;
                int hh2 = (gcol >> 6) & 7, dd2 = gcol & 63;
                int grow = m0 + nb8;
                int bb = grow >> 12, nn = grow & 4095;
                *(bf16x8*)&Vt[(((size_t)bb * 8 + hh2) * 64 + dd2) * 4096 + nn] = v;
            }
        }
    } else {
#pragma unroll
        for (int n = 0; n < NR; n++) {
            int col = n0 + wc + n * 16 + lr;
            float bcol = bias[col];
#pragma unroll
            for (int m = 0; m < MR; m++) {
#pragma unroll
                for (int r = 0; r < 4; r++) {
                    int row = m0 + wr + m * 16 + rq + r;
                    float v = acc[m][n][r] + bcol;
                    if (ACT == 1) v = gelu_fast(v);
                    size_t idx = (size_t)row * N + col;
                    if (RES) Cf[idx] += v;
                    else Cf[idx] = v;
                }
            }
        }
    }
}

// ---------------- K-feature GEMM (single pass, shift-invariant kmx=0) ----------------
__global__ __launch_bounds__(256) void feat_kernel(const bf16_t* __restrict__ qkvb,
                                                   const bf16_t* __restrict__ projb,
                                                   bf16_t* __restrict__ outp,
                                                   float* __restrict__ ksum_part) {
    int bid = blockIdx.x;
    int bh = bid >> 5, tile = bid & 31;
    int b = bh >> 3, hh = bh & 7;
    int tid = threadIdx.x, wv = tid >> 6, ln = tid & 63;
    __shared__ __attribute__((aligned(16))) bf16_t As[128 * 64];
    __shared__ __attribute__((aligned(16))) bf16_t Bs[256 * 64];
    __shared__ float diag_s[128];
    __shared__ float ksp_s[256];
    int n0 = tile * 128;
    int qoff = 512 + hh * 64;
    int lrow8 = ln >> 3;
    int lchunk = ((ln & 7) ^ (lrow8 & 7)) * 8;
#pragma unroll
    for (int i = 0; i < 4; i++) {
        int e = wv * 4 + i;
        size_t src = (size_t)(b * SEQN + n0 + e * 8 + lrow8) * 1024 + qoff + lchunk;
        __builtin_amdgcn_global_load_lds(AS1(qkvb + src), AS3(&As[e * 512]), 16, 0, 0);
    }
#pragma unroll
    for (int i = 0; i < 8; i++) {
        int e = wv * 8 + i;
        size_t src = (size_t)(e * 8 + lrow8) * 64 + lchunk;
        __builtin_amdgcn_global_load_lds(AS1(projb + src), AS3(&Bs[e * 512]), 16, 0, 0);
    }
    __syncthreads();
    if (tid < 128) {
        float s = 0.f;
#pragma unroll
        for (int c = 0; c < 8; c++) {
            bf16x8 v = *(const bf16x8*)&As[tid * 64 + ((c ^ (tid & 7)) * 8)];
#pragma unroll
            for (int j = 0; j < 8; j++) { float f = (float)v[j]; s += f * f; }
        }
        diag_s[tid] = s * (0.5f * DN * DN);
    }
    int wr = (wv >> 1) * 64, wc = (wv & 1) * 128;
    int lr = ln & 15, kg = ln >> 4, rq = kg * 4;
    f32x4v acc[4][8] = {};
#pragma unroll
    for (int ks = 0; ks < 2; ks++) {
        int g = ks * 4 + kg;
        bf16x8 af[4], bfv[8];
#pragma unroll
        for (int m = 0; m < 4; m++) {
            int row = wr + m * 16 + lr;
            af[m] = *(const bf16x8*)&As[row * 64 + ((g ^ (row & 7)) * 8)];
        }
#pragma unroll
        for (int n = 0; n < 8; n++) {
            int row = wc + n * 16 + lr;
            bfv[n] = *(const bf16x8*)&Bs[row * 64 + ((g ^ (row & 7)) * 8)];
        }
#pragma unroll
        for (int m = 0; m < 4; m++)
#pragma unroll
            for (int n = 0; n < 8; n++)
                acc[m][n] = __builtin_amdgcn_mfma_f32_16x16x32_bf16(af[m], bfv[n], acc[m][n], 0, 0, 0);
    }
    __syncthreads();   // diag_s visible to all
    float sj[8] = {};
#pragma unroll
    for (int m = 0; m < 4; m++) {
#pragma unroll
        for (int n = 0; n < 8; n++) {
            int col = wc + n * 16 + lr;
            bf16x4 pk;
#pragma unroll
            for (int r = 0; r < 4; r++) {
                int row = wr + m * 16 + rq + r;
                float val = RATIO * (__expf(acc[m][n][r] * DN - diag_s[row]) + EPSK);
                pk[r] = (bf16_t)val;
                sj[n] += val;
            }
            *(bf16x4*)&outp[((size_t)bh * MF + col) * 4096 + n0 + wr + m * 16 + rq] = pk;
        }
    }
#pragma unroll
    for (int n = 0; n < 8; n++) {
        sj[n] += __shfl_xor(sj[n], 16);
        sj[n] += __shfl_xor(sj[n], 32);
    }
    if (wv < 2 && ln < 16) {
#pragma unroll
        for (int n = 0; n < 8; n++) ksp_s[wc + n * 16 + ln] = sj[n];
    }
    __syncthreads();
    if (wv >= 2 && ln < 16) {
#pragma unroll
        for (int n = 0; n < 8; n++) ksp_s[wc + n * 16 + ln] += sj[n];
    }
    __syncthreads();
    ksum_part[(size_t)bid * 256 + tid] = ksp_s[tid];
}

// ---------------- ctx split-K GEMM ----------------
__global__ __launch_bounds__(256) void ctx_gemm(const bf16_t* __restrict__ KPt,
                                                const bf16_t* __restrict__ Vt,
                                                float* __restrict__ part) {
    int bh = blockIdx.y;
    int mtile = blockIdx.x & 1, kc = blockIdx.x >> 1;
    int m0 = mtile * 128, nb = kc * 512;
    int tid = threadIdx.x, wv = tid >> 6, ln = tid & 63;
    __shared__ __attribute__((aligned(16))) bf16_t As[128 * 64];
    __shared__ __attribute__((aligned(16))) bf16_t Bs[64 * 64];
    int lrow8 = ln >> 3;
    int lchunk = ((ln & 7) ^ (lrow8 & 7)) * 8;
    int lr = ln & 15, kg = ln >> 4, rq = kg * 4;
    int wr = wv * 32;
    f32x4v acc[2][4] = {};
    for (int kt = 0; kt < 8; kt++) {
        int noff = nb + kt * 64;
        __syncthreads();
#pragma unroll
        for (int i = 0; i < 4; i++) {
            int e = wv * 4 + i;
            __builtin_amdgcn_global_load_lds(
                AS1(KPt + ((size_t)bh * MF + m0 + e * 8 + lrow8) * 4096 + noff + lchunk),
                AS3(&As[e * 512]), 16, 0, 0);
        }
#pragma unroll
        for (int i = 0; i < 2; i++) {
            int e = wv * 2 + i;
            __builtin_amdgcn_global_load_lds(
                AS1(Vt + ((size_t)bh * 64 + e * 8 + lrow8) * 4096 + noff + lchunk),
                AS3(&Bs[e * 512]), 16, 0, 0);
        }
        __syncthreads();
#pragma unroll
        for (int ks = 0; ks < 2; ks++) {
            int g = ks * 4 + kg;
            bf16x8 af[2], bfv[4];
#pragma unroll
            for (int m = 0; m < 2; m++) {
                int row = wr + m * 16 + lr;
                af[m] = *(const bf16x8*)&As[row * 64 + ((g ^ (row & 7)) * 8)];
            }
#pragma unroll
            for (int n = 0; n < 4; n++) {
                int row = n * 16 + lr;
                bfv[n] = *(const bf16x8*)&Bs[row * 64 + ((g ^ (row & 7)) * 8)];
            }
#pragma unroll
            for (int m = 0; m < 2; m++)
#pragma unroll
                for (int n = 0; n < 4; n++)
                    acc[m][n] = __builtin_amdgcn_mfma_f32_16x16x32_bf16(af[m], bfv[n], acc[m][n], 0, 0, 0);
        }
    }
#pragma unroll
    for (int m = 0; m < 2; m++)
#pragma unroll
        for (int n = 0; n < 4; n++)
#pragma unroll
            for (int r = 0; r < 4; r++)
                part[((size_t)(kc * 16 + bh) * MF + m0 + wr + m * 16 + rq + r) * 64 + n * 16 + lr] =
                    acc[m][n][r];
}

// ---------------- ctx reduce -> ctx_t[bh][d][m] bf16; + ksum reduce ----------------
__global__ __launch_bounds__(256) void ctx_reduce_kernel(const float* __restrict__ part,
                                                         const float* __restrict__ ksum_part,
                                                         bf16_t* __restrict__ ctx_t,
                                                         float* __restrict__ ksum) {
    int bh = blockIdx.x;
    for (int it = 0; it < 64; it++) {
        int idx = it * 256 + threadIdx.x;
        int m = idx >> 6, d = idx & 63;
        float s = 0.f;
#pragma unroll
        for (int kc = 0; kc < 8; kc++)
            s += part[(size_t)(kc * 16 + bh) * 16384 + idx];
        ctx_t[((size_t)bh * 64 + d) * MF + m] = (bf16_t)s;
    }
    {
        float s = 0.f;
#pragma unroll
        for (int t = 0; t < 32; t++)
            s += ksum_part[((size_t)bh * 32 + t) * 256 + threadIdx.x];
        ksum[bh * MF + threadIdx.x] = s;
    }
}

// ---------------- fused Q-side: q-features + dinv + (qp@ctx)*dinv -> abuf ----------------
__global__ __launch_bounds__(256) void qfused_kernel(const bf16_t* __restrict__ qkvb,
                                                     const bf16_t* __restrict__ projb,
                                                     const bf16_t* __restrict__ ctx_t,
                                                     const float* __restrict__ ksumb,
                                                     bf16_t* __restrict__ abuf) {
    int bid = blockIdx.x;
    int bh = bid >> 5, tile = bid & 31;
    int b = bh >> 3, hh = bh & 7;
    int tid = threadIdx.x, wv = tid >> 6, ln = tid & 63;
    __shared__ __attribute__((aligned(16))) bf16_t Qs[128 * 64];
    __shared__ __attribute__((aligned(16))) bf16_t Ps[256 * 64];
    __shared__ __attribute__((aligned(16))) bf16_t Cs[64 * 256];
    __shared__ float diag_s[128];
    __shared__ float dsum_s[128];
    int n0 = tile * 128;
    int lrow8 = ln >> 3;
    int lchunk = ((ln & 7) ^ (lrow8 & 7)) * 8;
#pragma unroll
    for (int i = 0; i < 4; i++) {
        int e = wv * 4 + i;
        size_t src = (size_t)(b * SEQN + n0 + e * 8 + lrow8) * 1024 + hh * 64 + lchunk;
        __builtin_amdgcn_global_load_lds(AS1(qkvb + src), AS3(&Qs[e * 512]), 16, 0, 0);
    }
#pragma unroll
    for (int i = 0; i < 8; i++) {
        int e = wv * 8 + i;
        size_t src = (size_t)(e * 8 + lrow8) * 64 + lchunk;
        __builtin_amdgcn_global_load_lds(AS1(projb + src), AS3(&Ps[e * 512]), 16, 0, 0);
    }
#pragma unroll
    for (int i = 0; i < 8; i++) {
        int c = i * 256 + tid;
        int cb = i * 256 + (tid & ~63);
        int crow = c >> 5, cch = c & 31;
        size_t src = ((size_t)bh * 64 + crow) * 256 + (size_t)(cch ^ (crow & 7)) * 8;
        __builtin_amdgcn_global_load_lds(AS1(ctx_t + src), AS3(Cs + (size_t)cb * 8), 16, 0, 0);
    }
    int wr = (wv >> 1) * 64, wc = (wv & 1) * 128;
    int lr = ln & 15, kg = ln >> 4, rq = kg * 4;
    float ksum_r[8];
#pragma unroll
    for (int n = 0; n < 8; n++) ksum_r[n] = ksumb[bh * MF + wc + n * 16 + lr];
    __syncthreads();
    if (tid < 128) {
        float s = 0.f;
#pragma unroll
        for (int c = 0; c < 8; c++) {
            bf16x8 v = *(const bf16x8*)&Qs[tid * 64 + ((c ^ (tid & 7)) * 8)];
#pragma unroll
            for (int j = 0; j < 8; j++) { float f = (float)v[j]; s += f * f; }
        }
        diag_s[tid] = s * (0.5f * DN * DN);
    }
    f32x4v acc[4][8] = {};
#pragma unroll
    for (int ks = 0; ks < 2; ks++) {
        int g = ks * 4 + kg;
        bf16x8 af[4], bfv[8];
#pragma unroll
        for (int m = 0; m < 4; m++) {
            int row = wr + m * 16 + lr;
            af[m] = *(const bf16x8*)&Qs[row * 64 + ((g ^ (row & 7)) * 8)];
        }
#pragma unroll
        for (int n = 0; n < 8; n++) {
            int row = wc + n * 16 + lr;
            bfv[n] = *(const bf16x8*)&Ps[row * 64 + ((g ^ (row & 7)) * 8)];
        }
#pragma unroll
        for (int m = 0; m < 4; m++)
#pragma unroll
            for (int n = 0; n < 8; n++)
                acc[m][n] = __builtin_amdgcn_mfma_f32_16x16x32_bf16(af[m], bfv[n], acc[m][n], 0, 0, 0);
    }
    __syncthreads();   // diag_s visible
    float dsum_p[4][4];
#pragma unroll
    for (int m = 0; m < 4; m++) {
#pragma unroll
        for (int r = 0; r < 4; r++) {
            int row = wr + m * 16 + rq + r;
            float dg = diag_s[row];
            float ds = 0.f;
#pragma unroll
            for (int n = 0; n < 8; n++) {
                float val = RATIO * (__expf(acc[m][n][r] * DN - dg) + EPSK);
                acc[m][n][r] = val;
                ds += val * ksum_r[n];
            }
            dsum_p[m][r] = ds;
        }
    }
#pragma unroll
    for (int m = 0; m < 4; m++)
#pragma unroll
        for (int r = 0; r < 4; r++) {
#pragma unroll
            for (int mask = 1; mask < 16; mask <<= 1)
                dsum_p[m][r] += __shfl_xor(dsum_p[m][r], mask);
        }
    if ((wv & 1) == 0 && lr == 0) {
#pragma unroll
        for (int m = 0; m < 4; m++)
#pragma unroll
            for (int r = 0; r < 4; r++)
                dsum_s[wr + m * 16 + rq + r] = dsum_p[m][r];
    }
    __syncthreads();
    if ((wv & 1) == 1 && lr == 0) {
#pragma unroll
        for (int m = 0; m < 4; m++)
#pragma unroll
            for (int r = 0; r < 4; r++) {
                int row = wr + m * 16 + rq + r;
                dsum_s[row] = 1.0f / (dsum_s[row] + dsum_p[m][r]);
            }
    }
    __syncthreads();
    f32x4v acc_o[4][2] = {};
#pragma unroll
    for (int h = 0; h < 2; h++) {
        if ((wv & 1) == h) {
#pragma unroll
            for (int m = 0; m < 4; m++)
#pragma unroll
                for (int n = 0; n < 8; n++)
#pragma unroll
                    for (int r = 0; r < 4; r++) {
                        int row = wr + m * 16 + rq + r;
                        int ml = n * 16 + lr;
                        Ps[row * 128 + (((ml >> 3) ^ (row & 7)) * 8) + (ml & 7)] =
                            (bf16_t)acc[m][n][r];
                    }
        }
        __syncthreads();
#pragma unroll
        for (int ku = 0; ku < 4; ku++) {
            int g = ku * 4 + kg;
            bf16x8 af[4], bfv[2];
#pragma unroll
            for (int m = 0; m < 4; m++) {
                int row = wr + m * 16 + lr;
                af[m] = *(const bf16x8*)&Ps[row * 128 + ((g ^ (row & 7)) * 8)];
            }
#pragma unroll
            for (int n = 0; n < 2; n++) {
                int rowd = (wv & 1) * 32 + n * 16 + lr;
                int ch = (h * 16 + g) ^ (rowd & 7);
                bfv[n] = *(const bf16x8*)&Cs[(rowd * 32 + ch) * 8];
            }
#pragma unroll
            for (int m = 0; m < 4; m++)
#pragma unroll
                for (int n = 0; n < 2; n++)
                    acc_o[m][n] = __builtin_amdgcn_mfma_f32_16x16x32_bf16(af[m], bfv[n], acc_o[m][n], 0, 0, 0);
        }
        __syncthreads();
    }
#pragma unroll
    for (int m = 0; m < 4; m++) {
#pragma unroll
        for (int r = 0; r < 4; r++) {
            int rowl = wr + m * 16 + rq + r;
            float di = dsum_s[rowl];
            size_t obase = ((size_t)(b * SEQN + n0 + rowl)) * DMODEL + hh * 64;
#pragma unroll
            for (int n = 0; n < 2; n++) {
                int d = (wv & 1) * 32 + n * 16 + lr;
                abuf[obase + d] = (bf16_t)(acc_o[m][n][r] * di);
            }
        }
    }
}

extern "C" void kernel_launch(void* const* d_in, const int* in_sizes, int n_in,
                              void* d_out, int out_size, void* d_ws, size_t ws_size,
                              hipStream_t stream) {
    const float* x     = (const float*)d_in[0];
    const float* proj  = (const float*)d_in[1];
    const float* ln1_g = (const float*)d_in[2];
    const float* ln1_b = (const float*)d_in[3];
    const float* Wqkv  = (const float*)d_in[4];
    const float* bqkv  = (const float*)d_in[5];
    const float* Wo    = (const float*)d_in[6];
    const float* bo    = (const float*)d_in[7];
    const float* ln2_g = (const float*)d_in[8];
    const float* ln2_b = (const float*)d_in[9];
    const float* Wff1  = (const float*)d_in[10];
    const float* bff1  = (const float*)d_in[11];
    const float* Wff2  = (const float*)d_in[12];
    const float* bff2  = (const float*)d_in[13];

    float* h = (float*)d_out;
    char* ws = (char*)d_ws;
    bf16_t* KPt   = (bf16_t*)(ws);
    bf16_t* ybf   = (bf16_t*)(ws);               // [0, 8Mi)   (dead when KPt live)
    bf16_t* pWo   = (bf16_t*)(ws + 8388608);     // [8Mi,16Mi)
    bf16_t* pFF2  = (bf16_t*)(ws + 16777216);    // [16Mi,24Mi)
    bf16_t* qkvb  = (bf16_t*)(ws + 33554432);
    bf16_t* abufb = (bf16_t*)(ws + 50331648);
    float*  ctx_part  = (float*)(ws + 58720256);
    float*  ksum_part = (float*)(ws + 67108864);
    bf16_t* ffmidb    = (bf16_t*)(ws + 50331648);
    bf16_t* Vt    = (bf16_t*)(ws + 83886080);
    bf16_t* projb = (bf16_t*)(ws + 92274688);
    bf16_t* ctx_t = (bf16_t*)(ws + 92405760);
    float*  ksumb = (float*)(ws + 92930048);
    bf16_t* wbase = (bf16_t*)(ws + 93061120);
    const size_t WSLOT = 3407872;
    bool hoist = ws_size >= (size_t)93061120 + 4 * 6815744;

    hipMemcpyAsync(h, x, (size_t)NROWS * DMODEL * sizeof(float),
                   hipMemcpyDeviceToDevice, stream);
    pconv_kernel<<<64, 256, 0, stream>>>(proj, projb);
    if (hoist)
        wconv_all<<<dim3(3072, 4), 256, 0, stream>>>(Wqkv, Wo, Wff1, Wff2, wbase);

    for (int i = 0; i < DEPTH; i++) {
        const bf16_t* pj = projb + (size_t)i * MF * DH;
        if (!hoist)
            wconv_all<<<dim3(3072, 1), 256, 0, stream>>>(
                Wqkv + (size_t)i * 786432, Wo + (size_t)i * 262144,
                Wff1 + (size_t)i * 1048576, Wff2 + (size_t)i * 1048576, wbase);
        bf16_t* wl = wbase + (hoist ? (size_t)i * WSLOT : 0);
        bf16_t* wq_t = wl;
        bf16_t* wo_t = wl + 786432;
        bf16_t* w1_t = wl + 1048576;
        bf16_t* w2_t = wl + 2097152;

        if (i == 0)
            ln_kernel<<<NROWS, 256, 0, stream>>>(h, ln1_g, ln1_b, ybf);
        else
            ln_add_kernel<<<NROWS, 256, 0, stream>>>(h, pFF2, ln1_g + i * DMODEL,
                                                     ln1_b + i * DMODEL, ybf);
        gemm_pipe<128, 64, 32, 3, 0, 0, 0, 0, 1>
            <<<dim3(1536 / 64, NROWS / 128), 256, 0, stream>>>(
            ybf, wq_t, bqkv + i * 1536, nullptr, qkvb, Vt, 1536, 512);
        feat_kernel<<<512, 256, 0, stream>>>(qkvb, pj, KPt, ksum_part);
        ctx_gemm<<<dim3(16, 16), 256, 0, stream>>>(KPt, Vt, ctx_part);
        ctx_reduce_kernel<<<16, 256, 0, stream>>>(ctx_part, ksum_part, ctx_t, ksumb);
        qfused_kernel<<<512, 256, 0, stream>>>(qkvb, pj, ctx_t, ksumb, abufb);
        gemm_pipe<128, 64, 32, 3, 0, 0, 0, 1, 0>
            <<<dim3(512 / 64, NROWS / 128), 256, 0, stream>>>(
            abufb, wo_t, bo + i * DMODEL, nullptr, pWo, nullptr, 512, 512);

        ln_add_kernel<<<NROWS, 256, 0, stream>>>(h, pWo, ln2_g + i * DMODEL,
                                                 ln2_b + i * DMODEL, ybf);
        gemm_pipe<128, 64, 32, 3, 1, 0, 0, 1, 0>
            <<<dim3(2048 / 64, NROWS / 128), 256, 0, stream>>>(
            ybf, w1_t, bff1 + i * FFD, nullptr, ffmidb, nullptr, 2048, 512);
        gemm_pipe<128, 64, 32, 3, 0, 0, 0, 1, 0>
            <<<dim3(512 / 64, NROWS / 128), 256, 0, stream>>>(
            ffmidb, w2_t, bff2 + i * DMODEL, nullptr, pFF2, nullptr, 512, 2048);
    }
    add_kernel<<<4096, 256, 0, stream>>>(h, pFF2);
}

// Round 18
// 786.081 us; speedup vs baseline: 1.1442x; 1.0045x over previous
//
#include <hip/hip_runtime.h>
#include <math.h>

#define DEPTH 4
#define DMODEL 512
#define DH 64
#define MF 256
#define FFD 2048
#define SEQN 4096
#define NROWS 8192

typedef __bf16 bf16_t;
typedef bf16_t bf16x8 __attribute__((ext_vector_type(8)));
typedef bf16_t bf16x4 __attribute__((ext_vector_type(4)));
typedef bf16_t bf16x2 __attribute__((ext_vector_type(2)));
typedef float f32x4v __attribute__((ext_vector_type(4)));

static constexpr float DN = 0.35355339059327373f;   // 64^-0.25
static constexpr float RATIO = 0.0625f;             // 256^-0.5
static constexpr float EPSK = 1e-4f;

// tanh-approx GELU in sigmoid form
__device__ __forceinline__ float gelu_fast(float x) {
    float z2 = x * (1.5957691216f + 0.0713548162f * x * x);
    return x / (1.0f + __expf(-z2));
}

#define AS1(p) ((const __attribute__((address_space(1))) void*)(p))
#define AS3(p) ((__attribute__((address_space(3))) void*)(p))

template <int N> __device__ __forceinline__ void wait_vmcnt() {
    if constexpr (N == 0) asm volatile("s_waitcnt vmcnt(0)" ::: "memory");
    else if constexpr (N == 1) asm volatile("s_waitcnt vmcnt(1)" ::: "memory");
    else if constexpr (N == 2) asm volatile("s_waitcnt vmcnt(2)" ::: "memory");
    else if constexpr (N == 3) asm volatile("s_waitcnt vmcnt(3)" ::: "memory");
    else if constexpr (N == 4) asm volatile("s_waitcnt vmcnt(4)" ::: "memory");
    else if constexpr (N == 5) asm volatile("s_waitcnt vmcnt(5)" ::: "memory");
    else if constexpr (N == 6) asm volatile("s_waitcnt vmcnt(6)" ::: "memory");
    else if constexpr (N == 8) asm volatile("s_waitcnt vmcnt(8)" ::: "memory");
    else asm volatile("s_waitcnt vmcnt(12)" ::: "memory");
}

// ---------------- LayerNorm -> bf16 (no residual; src may be x or h) ----------------
__global__ __launch_bounds__(256) void ln_kernel(const float* __restrict__ h,
                                                 const float* __restrict__ g,
                                                 const float* __restrict__ b,
                                                 bf16_t* __restrict__ y) {
    int row = blockIdx.x, tid = threadIdx.x;
    const float* hr = h + (size_t)row * DMODEL;
    float v0 = hr[tid], v1 = hr[tid + 256];
    __shared__ float s_sum[256], s_sq[256];
    s_sum[tid] = v0 + v1;
    s_sq[tid] = v0 * v0 + v1 * v1;
    __syncthreads();
    for (int off = 128; off > 0; off >>= 1) {
        if (tid < off) { s_sum[tid] += s_sum[tid + off]; s_sq[tid] += s_sq[tid + off]; }
        __syncthreads();
    }
    float mu = s_sum[0] * (1.0f / DMODEL);
    float var = s_sq[0] * (1.0f / DMODEL) - mu * mu;
    float rstd = rsqrtf(var + 1e-5f);
    bf16_t* yr = y + (size_t)row * DMODEL;
    yr[tid]       = (bf16_t)((v0 - mu) * rstd * g[tid] + b[tid]);
    yr[tid + 256] = (bf16_t)((v1 - mu) * rstd * g[tid + 256] + b[tid + 256]);
}

// ---------------- fused: hout = hin + P (bf16); LayerNorm -> bf16 ----------------
__global__ __launch_bounds__(256) void ln_add_kernel(const float* __restrict__ hin,
                                                     float* __restrict__ hout,
                                                     const bf16_t* __restrict__ p,
                                                     const float* __restrict__ g,
                                                     const float* __restrict__ b,
                                                     bf16_t* __restrict__ y) {
    int row = blockIdx.x, tid = threadIdx.x;
    const float* hr = hin + (size_t)row * DMODEL;
    const bf16_t* pr = p + (size_t)row * DMODEL;
    float2 hv = *(const float2*)(hr + 2 * tid);
    bf16x2 pv = *(const bf16x2*)(pr + 2 * tid);
    float v0 = hv.x + (float)pv[0];
    float v1 = hv.y + (float)pv[1];
    float2 outv; outv.x = v0; outv.y = v1;
    *(float2*)(hout + (size_t)row * DMODEL + 2 * tid) = outv;
    __shared__ float s_sum[256], s_sq[256];
    s_sum[tid] = v0 + v1;
    s_sq[tid] = v0 * v0 + v1 * v1;
    __syncthreads();
    for (int off = 128; off > 0; off >>= 1) {
        if (tid < off) { s_sum[tid] += s_sum[tid + off]; s_sq[tid] += s_sq[tid + off]; }
        __syncthreads();
    }
    float mu = s_sum[0] * (1.0f / DMODEL);
    float var = s_sq[0] * (1.0f / DMODEL) - mu * mu;
    float rstd = rsqrtf(var + 1e-5f);
    bf16x2 ov;
    ov[0] = (bf16_t)((v0 - mu) * rstd * g[2 * tid] + b[2 * tid]);
    ov[1] = (bf16_t)((v1 - mu) * rstd * g[2 * tid + 1] + b[2 * tid + 1]);
    *(bf16x2*)(y + (size_t)row * DMODEL + 2 * tid) = ov;
}

// ---------------- tail: h += P (bf16) ----------------
__global__ __launch_bounds__(256) void add_kernel(float* __restrict__ h,
                                                  const bf16_t* __restrict__ p) {
    size_t i = ((size_t)blockIdx.x * 256 + threadIdx.x) * 4;
    float4 hv = *(const float4*)(h + i);
    bf16x4 pv = *(const bf16x4*)(p + i);
    hv.x += (float)pv[0]; hv.y += (float)pv[1];
    hv.z += (float)pv[2]; hv.w += (float)pv[3];
    *(float4*)(h + i) = hv;
}

// ---------------- weight transpose+convert; blockIdx.y = layer offset ----------------
__global__ __launch_bounds__(256) void wconv_all(const float* __restrict__ Wqkv,
                                                 const float* __restrict__ Wo,
                                                 const float* __restrict__ Wff1,
                                                 const float* __restrict__ Wff2,
                                                 bf16_t* __restrict__ wslot) {
    __shared__ float t[32][33];
    int layer = blockIdx.y;
    int bid = blockIdx.x;
    const float* W; bf16_t* Wt; int K, N, nx, lb;
    bf16_t* slot = wslot + (size_t)layer * 3407872;
    if (bid < 768)       { W = Wqkv + (size_t)layer * 786432;  Wt = slot;           K = 512;  N = 1536; nx = 48; lb = bid; }
    else if (bid < 1024) { W = Wo   + (size_t)layer * 262144;  Wt = slot + 786432;  K = 512;  N = 512;  nx = 16; lb = bid - 768; }
    else if (bid < 2048) { W = Wff1 + (size_t)layer * 1048576; Wt = slot + 1048576; K = 512;  N = 2048; nx = 64; lb = bid - 1024; }
    else                 { W = Wff2 + (size_t)layer * 1048576; Wt = slot + 2097152; K = 2048; N = 512;  nx = 16; lb = bid - 2048; }
    int n0 = (lb % nx) * 32, k0 = (lb / nx) * 32;
    int tx = threadIdx.x & 31, ty = threadIdx.x >> 5;
#pragma unroll
    for (int i = 0; i < 32; i += 8)
        t[ty + i][tx] = W[(size_t)(k0 + ty + i) * N + n0 + tx];
    __syncthreads();
#pragma unroll
    for (int i = 0; i < 32; i += 8)
        Wt[(size_t)(n0 + ty + i) * K + k0 + tx] = (bf16_t)t[tx][ty + i];
}

// ---------------- proj -> bf16 ----------------
__global__ __launch_bounds__(256) void pconv_kernel(const float* __restrict__ proj,
                                                    bf16_t* __restrict__ projb) {
    int i = (blockIdx.x * 256 + threadIdx.x) * 4;
    float4 v = *(const float4*)(proj + i);
    bf16x4 o;
    o[0] = (bf16_t)v.x; o[1] = (bf16_t)v.y; o[2] = (bf16_t)v.z; o[3] = (bf16_t)v.w;
    *(bf16x4*)(projb + i) = o;
}

// ---------------- 128x64 BK=32 P=3 pipelined MFMA GEMM, hoisted addressing ----------------
template <int BM, int BN, int BK, int P, int ACT, int RES, int WF, int WB, int QKVE>
__global__ __launch_bounds__(256) void gemm_pipe(const bf16_t* __restrict__ A,
                                                 const bf16_t* __restrict__ Bt,
                                                 const float* __restrict__ bias,
                                                 float* __restrict__ Cf,
                                                 bf16_t* __restrict__ Cb,
                                                 bf16_t* __restrict__ Vt,
                                                 int N, int K) {
    static_assert(BK == 32, "BK fixed at 32 (KS==1)");
    constexpr int MR = BM / 2 / 16;
    constexpr int NR = BN / 2 / 16;
    constexpr int CH = BK / 8;
    constexpr int SWZ = CH - 1;
    constexpr int TILE = (BM + BN) * BK;
    constexpr int L = TILE / 8 / 256;
    __shared__ __attribute__((aligned(16))) bf16_t smem[P * TILE];
    int tid = threadIdx.x;
    int wv = tid >> 6, ln = tid & 63;
    int gx = gridDim.x;
    int lin = blockIdx.y * gx + blockIdx.x;
    int per = (gx * gridDim.y) >> 3;
    int orig = (lin & 7) * per + (lin >> 3);
    int m0 = (orig / gx) * BM, n0 = (orig % gx) * BN;
    int wr = (wv >> 1) * (MR * 16), wc = (wv & 1) * (NR * 16);
    int lr = ln & 15, kq8 = ln >> 4;
    int nsteps = K / BK;

    const bf16_t* gsrc[L];
    int ldst[L];
#pragma unroll
    for (int i = 0; i < L; i++) {
        int c = i * 256 + tid;
        int cb = i * 256 + (tid & ~63);
        bool inA = (c < BM * CH);
        int cc = inA ? c : c - BM * CH;
        int row = cc / CH, ch = cc % CH;
        const bf16_t* mat = inA ? A : Bt;
        int r0 = inA ? m0 : n0;
        int chs = ch ^ ((row ^ (row >> 2)) & SWZ);
        gsrc[i] = mat + (size_t)(r0 + row) * K + chs * 8;
        ldst[i] = cb * 8;
    }
    auto stage = [&](int tile, int sb) {
        int k0 = tile * BK;
        bf16_t* dst = smem + sb * TILE;
#pragma unroll
        for (int i = 0; i < L; i++)
            __builtin_amdgcn_global_load_lds(AS1(gsrc[i] + k0), AS3(dst + ldst[i]), 16, 0, 0);
    };

    int aoff[MR], boff[NR];
#pragma unroll
    for (int m = 0; m < MR; m++) {
        int row = wr + m * 16 + lr;
        aoff[m] = (row * CH + (kq8 ^ ((row ^ (row >> 2)) & SWZ))) * 8;
    }
#pragma unroll
    for (int n = 0; n < NR; n++) {
        int row = wc + n * 16 + lr;
        boff[n] = BM * BK + (row * CH + (kq8 ^ ((row ^ (row >> 2)) & SWZ))) * 8;
    }

    f32x4v acc[MR][NR] = {};
#pragma unroll
    for (int p = 0; p < P - 1; ++p) stage(p, p);

    int cur = 0;
    for (int t = 0; t < nsteps; ++t) {
        int rem = nsteps - 1 - t;
        if (rem >= P - 2) wait_vmcnt<(P - 2) * L>();
        else if constexpr (P >= 4) {
            if (rem == 1) wait_vmcnt<L>(); else wait_vmcnt<0>();
        } else wait_vmcnt<0>();
        __builtin_amdgcn_s_barrier();
        asm volatile("" ::: "memory");
        if (t + P - 1 < nsteps) {
            int sb = cur - 1; if (sb < 0) sb = P - 1;
            stage(t + P - 1, sb);
        }
        const bf16_t* base = smem + cur * TILE;
        bf16x8 af[MR], bfr[NR];
#pragma unroll
        for (int m = 0; m < MR; m++) af[m] = *(const bf16x8*)&base[aoff[m]];
#pragma unroll
        for (int n = 0; n < NR; n++) bfr[n] = *(const bf16x8*)&base[boff[n]];
        __builtin_amdgcn_s_setprio(1);
#pragma unroll
        for (int m = 0; m < MR; m++)
#pragma unroll
            for (int n = 0; n < NR; n++)
                acc[m][n] = __builtin_amdgcn_mfma_f32_16x16x32_bf16(af[m], bfr[n], acc[m][n], 0, 0, 0);
        __builtin_amdgcn_s_setprio(0);
        cur = (cur + 1 == P) ? 0 : cur + 1;
    }
    int rq = (ln >> 4) * 4;
    if (WB || QKVE) {
        __syncthreads();
        bf16_t* T = smem;
        constexpr int S = BN + 8;
#pragma unroll
        for (int n = 0; n < NR; n++) {
            int col = wc + n * 16 + lr;
            float bcol = bias[n0 + col];
#pragma unroll
            for (int m = 0; m < MR; m++) {
#pragma unroll
                for (int r = 0; r < 4; r++) {
                    int row = wr + m * 16 + rq + r;
                    float v = acc[m][n][r] + bcol;
                    if (ACT == 1) v = gelu_fast(v);
                    int cs = (col & 7) | ((((col >> 3) ^ (row >> 3)) & (BN / 8 - 1)) << 3);
                    T[row * S + cs] = (bf16_t)v;
                }
            }
        }
        __syncthreads();
        if (!QKVE || n0 < 1024) {
            int ldc = QKVE ? 1024 : N;
#pragma unroll
            for (int i = 0; i < BM * BN / 8 / 256; i++) {
                int e = i * 2048 + tid * 8;
                int row = e / BN, c0 = e % BN;
                int ch = ((c0 >> 3) ^ (row >> 3)) & (BN / 8 - 1);
                bf16x8 v = *(const bf16x8*)&T[row * S + ch * 8];
                *(bf16x8*)&Cb[(size_t)(m0 + row) * ldc + n0 + c0] = v;
            }
        } else {
#pragma unroll
            for (int i = 0; i < BM * BN / 8 / 256; i++) {
                int u = i * 256 + tid;
                int d = u & (BN - 1), nb8 = (u / BN) * 8;
                bf16x8 v;
#pragma unroll
                for (int j = 0; j < 8; j++) {
                    int row = nb8 + j;
                    int cs = (d & 7) | ((((d >> 3) ^ (row >> 3)) & (BN / 8 - 1)) << 3);
                    v[j] = T[row * S + cs];
                }
                int gcol = n0 + d;
                int hh2 = (gcol >> 6) & 7, dd2 = gcol & 63;
                int grow = m0 + nb8;
                int bb = grow >> 12, nn = grow & 4095;
                *(bf16x8*)&Vt[(((size_t)bb * 8 + hh2) * 64 + dd2) * 4096 + nn] = v;
            }
        }
    } else {
#pragma unroll
        for (int n = 0; n < NR; n++) {
            int col = n0 + wc + n * 16 + lr;
            float bcol = bias[col];
#pragma unroll
            for (int m = 0; m < MR; m++) {
#pragma unroll
                for (int r = 0; r < 4; r++) {
                    int row = m0 + wr + m * 16 + rq + r;
                    float v = acc[m][n][r] + bcol;
                    if (ACT == 1) v = gelu_fast(v);
                    size_t idx = (size_t)row * N + col;
                    if (RES) Cf[idx] += v;
                    else Cf[idx] = v;
                }
            }
        }
    }
}

// ---------------- K-feature GEMM (single pass; coalesced KPt via LDS transpose) ----------------
__global__ __launch_bounds__(256) void feat_kernel(const bf16_t* __restrict__ qkvb,
                                                   const bf16_t* __restrict__ projb,
                                                   bf16_t* __restrict__ outp,
                                                   float* __restrict__ ksum_part) {
    int bid = blockIdx.x;
    int bh = bid >> 5, tile = bid & 31;
    int b = bh >> 3, hh = bh & 7;
    int tid = threadIdx.x, wv = tid >> 6, ln = tid & 63;
    __shared__ __attribute__((aligned(16))) bf16_t AsBs[128 * 64 + 256 * 64];
    bf16_t* As = AsBs;
    bf16_t* Bs = AsBs + 128 * 64;
    __shared__ float diag_s[128];
    __shared__ float ksp_s[256];
    int n0 = tile * 128;
    int qoff = 512 + hh * 64;
    int lrow8 = ln >> 3;
    int lchunk = ((ln & 7) ^ (lrow8 & 7)) * 8;
#pragma unroll
    for (int i = 0; i < 4; i++) {
        int e = wv * 4 + i;
        size_t src = (size_t)(b * SEQN + n0 + e * 8 + lrow8) * 1024 + qoff + lchunk;
        __builtin_amdgcn_global_load_lds(AS1(qkvb + src), AS3(&As[e * 512]), 16, 0, 0);
    }
#pragma unroll
    for (int i = 0; i < 8; i++) {
        int e = wv * 8 + i;
        size_t src = (size_t)(e * 8 + lrow8) * 64 + lchunk;
        __builtin_amdgcn_global_load_lds(AS1(projb + src), AS3(&Bs[e * 512]), 16, 0, 0);
    }
    __syncthreads();
    if (tid < 128) {
        float s = 0.f;
#pragma unroll
        for (int c = 0; c < 8; c++) {
            bf16x8 v = *(const bf16x8*)&As[tid * 64 + ((c ^ (tid & 7)) * 8)];
#pragma unroll
            for (int j = 0; j < 8; j++) { float f = (float)v[j]; s += f * f; }
        }
        diag_s[tid] = s * (0.5f * DN * DN);
    }
    int wr = (wv >> 1) * 64, wc = (wv & 1) * 128;
    int lr = ln & 15, kg = ln >> 4, rq = kg * 4;
    f32x4v acc[4][8] = {};
#pragma unroll
    for (int ks = 0; ks < 2; ks++) {
        int g = ks * 4 + kg;
        bf16x8 af[4], bfv[8];
#pragma unroll
        for (int m = 0; m < 4; m++) {
            int row = wr + m * 16 + lr;
            af[m] = *(const bf16x8*)&As[row * 64 + ((g ^ (row & 7)) * 8)];
        }
#pragma unroll
        for (int n = 0; n < 8; n++) {
            int row = wc + n * 16 + lr;
            bfv[n] = *(const bf16x8*)&Bs[row * 64 + ((g ^ (row & 7)) * 8)];
        }
#pragma unroll
        for (int m = 0; m < 4; m++)
#pragma unroll
            for (int n = 0; n < 8; n++)
                acc[m][n] = __builtin_amdgcn_mfma_f32_16x16x32_bf16(af[m], bfv[n], acc[m][n], 0, 0, 0);
    }
    __syncthreads();   // diag_s visible to all
    // kp values into acc; ksum partials
    float sj[8] = {};
#pragma unroll
    for (int m = 0; m < 4; m++) {
#pragma unroll
        for (int n = 0; n < 8; n++) {
#pragma unroll
            for (int r = 0; r < 4; r++) {
                int row = wr + m * 16 + rq + r;
                float val = RATIO * (__expf(acc[m][n][r] * DN - diag_s[row]) + EPSK);
                acc[m][n][r] = val;
                sj[n] += val;
            }
        }
    }
#pragma unroll
    for (int n = 0; n < 8; n++) {
        sj[n] += __shfl_xor(sj[n], 16);
        sj[n] += __shfl_xor(sj[n], 32);
    }
    if (wv < 2 && ln < 16) {
#pragma unroll
        for (int n = 0; n < 8; n++) ksp_s[wc + n * 16 + ln] = sj[n];
    }
    __syncthreads();
    if (wv >= 2 && ln < 16) {
#pragma unroll
        for (int n = 0; n < 8; n++) ksp_s[wc + n * 16 + ln] += sj[n];
    }
    __syncthreads();   // ksp done; all As/Bs consumers past -> safe to reuse as T
    ksum_part[(size_t)bid * 256 + tid] = ksp_s[tid];
    // transpose-write KPt via LDS, two 128-col halves
    bf16_t* T = AsBs;                    // 128 x 136 bf16 = 34 KB
#pragma unroll
    for (int hf = 0; hf < 2; hf++) {
        if ((wv & 1) == hf) {
#pragma unroll
            for (int n = 0; n < 8; n++) {
                int mm = n * 16 + lr;            // 0..127 within half
#pragma unroll
                for (int m = 0; m < 4; m++) {
                    int nnb = wr + m * 16 + rq;  // multiple of 4
                    bf16x4 v;
#pragma unroll
                    for (int r = 0; r < 4; r++) v[r] = (bf16_t)acc[m][n][r];
                    *(bf16x4*)&T[mm * 136 + nnb] = v;
                }
            }
        }
        __syncthreads();
#pragma unroll
        for (int i = 0; i < 8; i++) {
            int u = i * 256 + tid;
            int mm = u >> 4, nc = u & 15;
            bf16x8 v = *(const bf16x8*)&T[mm * 136 + nc * 8];
            *(bf16x8*)&outp[((size_t)bh * MF + hf * 128 + mm) * 4096 + n0 + nc * 8] = v;
        }
        __syncthreads();
    }
}

// ---------------- ctx split-K GEMM ----------------
__global__ __launch_bounds__(256) void ctx_gemm(const bf16_t* __restrict__ KPt,
                                                const bf16_t* __restrict__ Vt,
                                                float* __restrict__ part) {
    int bh = blockIdx.y;
    int mtile = blockIdx.x & 1, kc = blockIdx.x >> 1;
    int m0 = mtile * 128, nb = kc * 512;
    int tid = threadIdx.x, wv = tid >> 6, ln = tid & 63;
    __shared__ __attribute__((aligned(16))) bf16_t As[128 * 64];
    __shared__ __attribute__((aligned(16))) bf16_t Bs[64 * 64];
    int lrow8 = ln >> 3;
    int lchunk = ((ln & 7) ^ (lrow8 & 7)) * 8;
    int lr = ln & 15, kg = ln >> 4, rq = kg * 4;
    int wr = wv * 32;
    f32x4v acc[2][4] = {};
    for (int kt = 0; kt < 8; kt++) {
        int noff = nb + kt * 64;
        __syncthreads();
#pragma unroll
        for (int i = 0; i < 4; i++) {
            int e = wv * 4 + i;
            __builtin_amdgcn_global_load_lds(
                AS1(KPt + ((size_t)bh * MF + m0 + e * 8 + lrow8) * 4096 + noff + lchunk),
                AS3(&As[e * 512]), 16, 0, 0);
        }
#pragma unroll
        for (int i = 0; i < 2; i++) {
            int e = wv * 2 + i;
            __builtin_amdgcn_global_load_lds(
                AS1(Vt + ((size_t)bh * 64 + e * 8 + lrow8) * 4096 + noff + lchunk),
                AS3(&Bs[e * 512]), 16, 0, 0);
        }
        __syncthreads();
#pragma unroll
        for (int ks = 0; ks < 2; ks++) {
            int g = ks * 4 + kg;
            bf16x8 af[2], bfv[4];
#pragma unroll
            for (int m = 0; m < 2; m++) {
                int row = wr + m * 16 + lr;
                af[m] = *(const bf16x8*)&As[row * 64 + ((g ^ (row & 7)) * 8)];
            }
#pragma unroll
            for (int n = 0; n < 4; n++) {
                int row = n * 16 + lr;
                bfv[n] = *(const bf16x8*)&Bs[row * 64 + ((g ^ (row & 7)) * 8)];
            }
#pragma unroll
            for (int m = 0; m < 2; m++)
#pragma unroll
                for (int n = 0; n < 4; n++)
                    acc[m][n] = __builtin_amdgcn_mfma_f32_16x16x32_bf16(af[m], bfv[n], acc[m][n], 0, 0, 0);
        }
    }
#pragma unroll
    for (int m = 0; m < 2; m++)
#pragma unroll
        for (int n = 0; n < 4; n++)
#pragma unroll
            for (int r = 0; r < 4; r++)
                part[((size_t)(kc * 16 + bh) * MF + m0 + wr + m * 16 + rq + r) * 64 + n * 16 + lr] =
                    acc[m][n][r];
}

// ---------------- ctx reduce -> ctx_t[bh][d][m] bf16; + ksum reduce ----------------
__global__ __launch_bounds__(256) void ctx_reduce_kernel(const float* __restrict__ part,
                                                         const float* __restrict__ ksum_part,
                                                         bf16_t* __restrict__ ctx_t,
                                                         float* __restrict__ ksum) {
    int bh = blockIdx.x;
    for (int it = 0; it < 64; it++) {
        int idx = it * 256 + threadIdx.x;
        int m = idx >> 6, d = idx & 63;
        float s = 0.f;
#pragma unroll
        for (int kc = 0; kc < 8; kc++)
            s += part[(size_t)(kc * 16 + bh) * 16384 + idx];
        ctx_t[((size_t)bh * 64 + d) * MF + m] = (bf16_t)s;
    }
    {
        float s = 0.f;
#pragma unroll
        for (int t = 0; t < 32; t++)
            s += ksum_part[((size_t)bh * 32 + t) * 256 + threadIdx.x];
        ksum[bh * MF + threadIdx.x] = s;
    }
}

// ---------------- fused Q-side: q-features + dinv + (qp@ctx)*dinv -> abuf ----------------
__global__ __launch_bounds__(256) void qfused_kernel(const bf16_t* __restrict__ qkvb,
                                                     const bf16_t* __restrict__ projb,
                                                     const bf16_t* __restrict__ ctx_t,
                                                     const float* __restrict__ ksumb,
                                                     bf16_t* __restrict__ abuf) {
    int bid = blockIdx.x;
    int bh = bid >> 5, tile = bid & 31;
    int b = bh >> 3, hh = bh & 7;
    int tid = threadIdx.x, wv = tid >> 6, ln = tid & 63;
    __shared__ __attribute__((aligned(16))) bf16_t Qs[128 * 64];
    __shared__ __attribute__((aligned(16))) bf16_t Ps[256 * 64];
    __shared__ __attribute__((aligned(16))) bf16_t Cs[64 * 256];
    __shared__ float diag_s[128];
    __shared__ float dsum_s[128];
    int n0 = tile * 128;
    int lrow8 = ln >> 3;
    int lchunk = ((ln & 7) ^ (lrow8 & 7)) * 8;
#pragma unroll
    for (int i = 0; i < 4; i++) {
        int e = wv * 4 + i;
        size_t src = (size_t)(b * SEQN + n0 + e * 8 + lrow8) * 1024 + hh * 64 + lchunk;
        __builtin_amdgcn_global_load_lds(AS1(qkvb + src), AS3(&Qs[e * 512]), 16, 0, 0);
    }
#pragma unroll
    for (int i = 0; i < 8; i++) {
        int e = wv * 8 + i;
        size_t src = (size_t)(e * 8 + lrow8) * 64 + lchunk;
        __builtin_amdgcn_global_load_lds(AS1(projb + src), AS3(&Ps[e * 512]), 16, 0, 0);
    }
#pragma unroll
    for (int i = 0; i < 8; i++) {
        int c = i * 256 + tid;
        int cb = i * 256 + (tid & ~63);
        int crow = c >> 5, cch = c & 31;
        size_t src = ((size_t)bh * 64 + crow) * 256 + (size_t)(cch ^ (crow & 7)) * 8;
        __builtin_amdgcn_global_load_lds(AS1(ctx_t + src), AS3(Cs + (size_t)cb * 8), 16, 0, 0);
    }
    int wr = (wv >> 1) * 64, wc = (wv & 1) * 128;
    int lr = ln & 15, kg = ln >> 4, rq = kg * 4;
    float ksum_r[8];
#pragma unroll
    for (int n = 0; n < 8; n++) ksum_r[n] = ksumb[bh * MF + wc + n * 16 + lr];
    __syncthreads();
    if (tid < 128) {
        float s = 0.f;
#pragma unroll
        for (int c = 0; c < 8; c++) {
            bf16x8 v = *(const bf16x8*)&Qs[tid * 64 + ((c ^ (tid & 7)) * 8)];
#pragma unroll
            for (int j = 0; j < 8; j++) { float f = (float)v[j]; s += f * f; }
        }
        diag_s[tid] = s * (0.5f * DN * DN);
    }
    f32x4v acc[4][8] = {};
#pragma unroll
    for (int ks = 0; ks < 2; ks++) {
        int g = ks * 4 + kg;
        bf16x8 af[4], bfv[8];
#pragma unroll
        for (int m = 0; m < 4; m++) {
            int row = wr + m * 16 + lr;
            af[m] = *(const bf16x8*)&Qs[row * 64 + ((g ^ (row & 7)) * 8)];
        }
#pragma unroll
        for (int n = 0; n < 8; n++) {
            int row = wc + n * 16 + lr;
            bfv[n] = *(const bf16x8*)&Ps[row * 64 + ((g ^ (row & 7)) * 8)];
        }
#pragma unroll
        for (int m = 0; m < 4; m++)
#pragma unroll
            for (int n = 0; n < 8; n++)
                acc[m][n] = __builtin_amdgcn_mfma_f32_16x16x32_bf16(af[m], bfv[n], acc[m][n], 0, 0, 0);
    }
    __syncthreads();   // diag_s visible
    float dsum_p[4][4];
#pragma unroll
    for (int m = 0; m < 4; m++) {
#pragma unroll
        for (int r = 0; r < 4; r++) {
            int row = wr + m * 16 + rq + r;
            float dg = diag_s[row];
            float ds = 0.f;
#pragma unroll
            for (int n = 0; n < 8; n++) {
                float val = RATIO * (__expf(acc[m][n][r] * DN - dg) + EPSK);
                acc[m][n][r] = val;
                ds += val * ksum_r[n];
            }
            dsum_p[m][r] = ds;
        }
    }
#pragma unroll
    for (int m = 0; m < 4; m++)
#pragma unroll
        for (int r = 0; r < 4; r++) {
#pragma unroll
            for (int mask = 1; mask < 16; mask <<= 1)
                dsum_p[m][r] += __shfl_xor(dsum_p[m][r], mask);
        }
    if ((wv & 1) == 0 && lr == 0) {
#pragma unroll
        for (int m = 0; m < 4; m++)
#pragma unroll
            for (int r = 0; r < 4; r++)
                dsum_s[wr + m * 16 + rq + r] = dsum_p[m][r];
    }
    __syncthreads();
    if ((wv & 1) == 1 && lr == 0) {
#pragma unroll
        for (int m = 0; m < 4; m++)
#pragma unroll
            for (int r = 0; r < 4; r++) {
                int row = wr + m * 16 + rq + r;
                dsum_s[row] = 1.0f / (dsum_s[row] + dsum_p[m][r]);
            }
    }
    __syncthreads();
    f32x4v acc_o[4][2] = {};
#pragma unroll
    for (int h = 0; h < 2; h++) {
        if ((wv & 1) == h) {
#pragma unroll
            for (int m = 0; m < 4; m++)
#pragma unroll
                for (int n = 0; n < 8; n++)
#pragma unroll
                    for (int r = 0; r < 4; r++) {
                        int row = wr + m * 16 + rq + r;
                        int ml = n * 16 + lr;
                        Ps[row * 128 + (((ml >> 3) ^ (row & 7)) * 8) + (ml & 7)] =
                            (bf16_t)acc[m][n][r];
                    }
        }
        __syncthreads();
#pragma unroll
        for (int ku = 0; ku < 4; ku++) {
            int g = ku * 4 + kg;
            bf16x8 af[4], bfv[2];
#pragma unroll
            for (int m = 0; m < 4; m++) {
                int row = wr + m * 16 + lr;
                af[m] = *(const bf16x8*)&Ps[row * 128 + ((g ^ (row & 7)) * 8)];
            }
#pragma unroll
            for (int n = 0; n < 2; n++) {
                int rowd = (wv & 1) * 32 + n * 16 + lr;
                int ch = (h * 16 + g) ^ (rowd & 7);
                bfv[n] = *(const bf16x8*)&Cs[(rowd * 32 + ch) * 8];
            }
#pragma unroll
            for (int m = 0; m < 4; m++)
#pragma unroll
                for (int n = 0; n < 2; n++)
                    acc_o[m][n] = __builtin_amdgcn_mfma_f32_16x16x32_bf16(af[m], bfv[n], acc_o[m][n], 0, 0, 0);
        }
        __syncthreads();
    }
#pragma unroll
    for (int m = 0; m < 4; m++) {
#pragma unroll
        for (int r = 0; r < 4; r++) {
            int rowl = wr + m * 16 + rq + r;
            float di = dsum_s[rowl];
            size_t obase = ((size_t)(b * SEQN + n0 + rowl)) * DMODEL + hh * 64;
#pragma unroll
            for (int n = 0; n < 2; n++) {
                int d = (wv & 1) * 32 + n * 16 + lr;
                abuf[obase + d] = (bf16_t)(acc_o[m][n][r] * di);
            }
        }
    }
}

extern "C" void kernel_launch(void* const* d_in, const int* in_sizes, int n_in,
                              void* d_out, int out_size, void* d_ws, size_t ws_size,
                              hipStream_t stream) {
    const float* x     = (const float*)d_in[0];
    const float* proj  = (const float*)d_in[1];
    const float* ln1_g = (const float*)d_in[2];
    const float* ln1_b = (const float*)d_in[3];
    const float* Wqkv  = (const float*)d_in[4];
    const float* bqkv  = (const float*)d_in[5];
    const float* Wo    = (const float*)d_in[6];
    const float* bo    = (const float*)d_in[7];
    const float* ln2_g = (const float*)d_in[8];
    const float* ln2_b = (const float*)d_in[9];
    const float* Wff1  = (const float*)d_in[10];
    const float* bff1  = (const float*)d_in[11];
    const float* Wff2  = (const float*)d_in[12];
    const float* bff2  = (const float*)d_in[13];

    float* h = (float*)d_out;
    char* ws = (char*)d_ws;
    bf16_t* KPt   = (bf16_t*)(ws);
    bf16_t* ybf   = (bf16_t*)(ws);               // [0, 8Mi)   (dead when KPt live)
    bf16_t* pWo   = (bf16_t*)(ws + 8388608);     // [8Mi,16Mi)
    bf16_t* pFF2  = (bf16_t*)(ws + 16777216);    // [16Mi,24Mi)
    bf16_t* qkvb  = (bf16_t*)(ws + 33554432);
    bf16_t* abufb = (bf16_t*)(ws + 50331648);
    float*  ctx_part  = (float*)(ws + 58720256);
    float*  ksum_part = (float*)(ws + 67108864);
    bf16_t* ffmidb    = (bf16_t*)(ws + 50331648);
    bf16_t* Vt    = (bf16_t*)(ws + 83886080);
    bf16_t* projb = (bf16_t*)(ws + 92274688);
    bf16_t* ctx_t = (bf16_t*)(ws + 92405760);
    float*  ksumb = (float*)(ws + 92930048);
    bf16_t* wbase = (bf16_t*)(ws + 93061120);
    const size_t WSLOT = 3407872;
    bool hoist = ws_size >= (size_t)93061120 + 4 * 6815744;

    pconv_kernel<<<64, 256, 0, stream>>>(proj, projb);
    if (hoist)
        wconv_all<<<dim3(3072, 4), 256, 0, stream>>>(Wqkv, Wo, Wff1, Wff2, wbase);

    for (int i = 0; i < DEPTH; i++) {
        const bf16_t* pj = projb + (size_t)i * MF * DH;
        if (!hoist)
            wconv_all<<<dim3(3072, 1), 256, 0, stream>>>(
                Wqkv + (size_t)i * 786432, Wo + (size_t)i * 262144,
                Wff1 + (size_t)i * 1048576, Wff2 + (size_t)i * 1048576, wbase);
        bf16_t* wl = wbase + (hoist ? (size_t)i * WSLOT : 0);
        bf16_t* wq_t = wl;
        bf16_t* wo_t = wl + 786432;
        bf16_t* w1_t = wl + 1048576;
        bf16_t* w2_t = wl + 2097152;

        if (i == 0)
            ln_kernel<<<NROWS, 256, 0, stream>>>(x, ln1_g, ln1_b, ybf);
        else
            ln_add_kernel<<<NROWS, 256, 0, stream>>>(h, h, pFF2, ln1_g + i * DMODEL,
                                                     ln1_b + i * DMODEL, ybf);
        gemm_pipe<128, 64, 32, 3, 0, 0, 0, 0, 1>
            <<<dim3(1536 / 64, NROWS / 128), 256, 0, stream>>>(
            ybf, wq_t, bqkv + i * 1536, nullptr, qkvb, Vt, 1536, 512);
        feat_kernel<<<512, 256, 0, stream>>>(qkvb, pj, KPt, ksum_part);
        ctx_gemm<<<dim3(16, 16), 256, 0, stream>>>(KPt, Vt, ctx_part);
        ctx_reduce_kernel<<<16, 256, 0, stream>>>(ctx_part, ksum_part, ctx_t, ksumb);
        qfused_kernel<<<512, 256, 0, stream>>>(qkvb, pj, ctx_t, ksumb, abufb);
        gemm_pipe<128, 64, 32, 3, 0, 0, 0, 1, 0>
            <<<dim3(512 / 64, NROWS / 128), 256, 0, stream>>>(
            abufb, wo_t, bo + i * DMODEL, nullptr, pWo, nullptr, 512, 512);

        ln_add_kernel<<<NROWS, 256, 0, stream>>>(i == 0 ? x : h, h, pWo,
                                                 ln2_g + i * DMODEL,
                                                 ln2_b + i * DMODEL, ybf);
        gemm_pipe<128, 64, 32, 3, 1, 0, 0, 1, 0>
            <<<dim3(2048 / 64, NROWS / 128), 256, 0, stream>>>(
            ybf, w1_t, bff1 + i * FFD, nullptr, ffmidb, nullptr, 2048, 512);
        gemm_pipe<128, 64, 32, 3, 0, 0, 0, 1, 0>
            <<<dim3(512 / 64, NROWS / 128), 256, 0, stream>>>(
            ffmidb, w2_t, bff2 + i * DMODEL, nullptr, pFF2, nullptr, 512, 2048);
    }
    add_kernel<<<4096, 256, 0, stream>>>(h, pFF2);
}